// Round 7
// baseline (306.481 us; speedup 1.0000x reference)
//
#include <hip/hip_runtime.h>

#define S_LEN 4096
#define DMODEL 64
#define QBLK 64
#define KBLK 32
#define NKT (S_LEN / KBLK)                  // 128 k-steps total
#define NSPLIT 4
#define NKT_S (NKT / NSPLIT)                // 32 k-steps per split
#define NROWS ((size_t)8 * S_LEN)           // 32768 (b,q) rows
#define NELEM ((size_t)8 * S_LEN * DMODEL)  // per-tensor elements (Q/K/V)

typedef __attribute__((ext_vector_type(8))) short bf16x8;
typedef __attribute__((ext_vector_type(4))) float f32x4;
typedef __attribute__((ext_vector_type(4))) unsigned short us4;

__device__ __forceinline__ unsigned short f2bf(float f) {
    unsigned int u = __builtin_bit_cast(unsigned int, f);
    u += 0x7FFFu + ((u >> 16) & 1u);   // round-to-nearest-even
    return (unsigned short)(u >> 16);
}

__device__ __forceinline__ bf16x8 cvt8(const float* __restrict__ p) {
    f32x4 a = *(const f32x4*)p;
    f32x4 b = *(const f32x4*)(p + 4);
    bf16x8 r;
    r[0] = (short)f2bf(a[0]); r[1] = (short)f2bf(a[1]);
    r[2] = (short)f2bf(a[2]); r[3] = (short)f2bf(a[3]);
    r[4] = (short)f2bf(b[0]); r[5] = (short)f2bf(b[1]);
    r[6] = (short)f2bf(b[2]); r[7] = (short)f2bf(b[3]);
    return r;
}

// ---- K: fp32 -> bf16, layout unchanged ----
__global__ __launch_bounds__(256)
void convert_k(const float* __restrict__ src, unsigned short* __restrict__ dst, int n4) {
    int i = blockIdx.x * blockDim.x + threadIdx.x;
    const int stride = gridDim.x * blockDim.x;
    for (; i < n4; i += stride) {
        f32x4 v = ((const f32x4*)src)[i];
        us4 o;
        o[0] = f2bf(v[0]); o[1] = f2bf(v[1]); o[2] = f2bf(v[2]); o[3] = f2bf(v[3]);
        ((us4*)dst)[i] = o;
    }
}

// ---- V: fp32 [b][k][d] -> bf16 Vta[b][d][p(k)]; p chosen so a contiguous bf16x8 at
//      [d][kb + g*8] holds keys kb + 16*(e>>2) + 4g + (e&3) (matches pf slots) ----
__global__ __launch_bounds__(256)
void convert_v(const float* __restrict__ V, unsigned short* __restrict__ Vta) {
    __shared__ unsigned short lds[64][72];
    const int t  = threadIdx.x;
    const int b  = blockIdx.x >> 6;
    const int k0 = (blockIdx.x & 63) * 64;

    {   // load 64 keys x 64 dims, cvt to bf16 into LDS
        const int kl = t >> 2, dseg = (t & 3) * 16;
        const float* src = V + ((size_t)(b * S_LEN + k0 + kl)) * DMODEL + dseg;
        #pragma unroll
        for (int i = 0; i < 4; ++i) {
            f32x4 v = *(const f32x4*)(src + i * 4);
            lds[kl][dseg + i * 4 + 0] = f2bf(v[0]);
            lds[kl][dseg + i * 4 + 1] = f2bf(v[1]);
            lds[kl][dseg + i * 4 + 2] = f2bf(v[2]);
            lds[kl][dseg + i * 4 + 3] = f2bf(v[3]);
        }
    }
    __syncthreads();
    {   // write transposed+permuted rows
        const int d = t >> 2, sub = t & 3;
        const int grp = sub >> 1;
        unsigned short* dst = Vta + ((size_t)b * DMODEL + d) * S_LEN + k0 + sub * 16;
        us4 o0, o1, o2, o3;
        #pragma unroll
        for (int m = 0; m < 16; ++m) {
            const int q  = (sub & 1) * 16 + m;
            const int g  = (q >> 3) & 3, hi = (q >> 2) & 1, r = q & 3;
            const unsigned short val = lds[grp * 32 + 16 * hi + 4 * g + r][d];
            if (m < 4)       o0[m]      = val;
            else if (m < 8)  o1[m - 4]  = val;
            else if (m < 12) o2[m - 8]  = val;
            else             o3[m - 12] = val;
        }
        *(us4*)(dst)      = o0;
        *(us4*)(dst + 4)  = o1;
        *(us4*)(dst + 8)  = o2;
        *(us4*)(dst + 12) = o3;
    }
}

// ---- split-K attention: each block does 1024 keys, writes partial (acc, lsum) ----
__global__ __launch_bounds__(256)
void attn_split(const float* __restrict__ Q,
                const unsigned short* __restrict__ Kw,
                const unsigned short* __restrict__ Vta,
                const float* __restrict__ M,
                float* __restrict__ Pacc,
                float* __restrict__ Plsum) {
    const int tid  = threadIdx.x;
    const int wave = tid >> 6;
    const int lane = tid & 63;
    const int g    = lane >> 4;
    const int j    = lane & 15;

    const int bid  = blockIdx.x;
    const int b    = bid & 7;            // batch -> XCD co-location for K/V
    const int qt   = (bid >> 3) & 63;    // q tile 0..63
    const int sp   = bid >> 9;           // split 0..3
    const int qrow = qt * QBLK + wave * 16 + j;
    const size_t row = (size_t)b * S_LEN + qrow;

    const float* Qb = Q + (size_t)b * S_LEN * DMODEL;
    const bf16x8 qf0 = cvt8(Qb + (size_t)qrow * DMODEL + g * 8);
    const bf16x8 qf1 = cvt8(Qb + (size_t)qrow * DMODEL + g * 8 + 32);

    f32x4 acc[4];
    #pragma unroll
    for (int dt = 0; dt < 4; ++dt) acc[dt] = f32x4{0.f, 0.f, 0.f, 0.f};
    float lsum = 0.f;

    const unsigned short* Kb  = Kw  + (size_t)b * S_LEN * DMODEL;
    const unsigned short* Vtb = Vta + (size_t)b * DMODEL * S_LEN;
    const float* mrow = M + (size_t)qrow * S_LEN;

    const int kt0 = sp * NKT_S;
    #pragma unroll 2
    for (int kt = kt0; kt < kt0 + NKT_S; ++kt) {
        const int kb = kt * KBLK;

        bf16x8 kf00 = *(const bf16x8*)(Kb + (size_t)(kb + j) * DMODEL + g * 8);
        bf16x8 kf01 = *(const bf16x8*)(Kb + (size_t)(kb + j) * DMODEL + g * 8 + 32);
        bf16x8 kf10 = *(const bf16x8*)(Kb + (size_t)(kb + 16 + j) * DMODEL + g * 8);
        bf16x8 kf11 = *(const bf16x8*)(Kb + (size_t)(kb + 16 + j) * DMODEL + g * 8 + 32);

        f32x4 st0 = {0.f, 0.f, 0.f, 0.f};
        f32x4 st1 = {0.f, 0.f, 0.f, 0.f};
        st0 = __builtin_amdgcn_mfma_f32_16x16x32_bf16(kf00, qf0, st0, 0, 0, 0);
        st0 = __builtin_amdgcn_mfma_f32_16x16x32_bf16(kf01, qf1, st0, 0, 0, 0);
        st1 = __builtin_amdgcn_mfma_f32_16x16x32_bf16(kf10, qf0, st1, 0, 0, 0);
        st1 = __builtin_amdgcn_mfma_f32_16x16x32_bf16(kf11, qf1, st1, 0, 0, 0);

        f32x4 m0 = *(const f32x4*)(mrow + kb + g * 4);
        f32x4 m1 = *(const f32x4*)(mrow + kb + 16 + g * 4);

        bf16x8 pf;   // slot e holds key kb + 16*(e>>2) + 4g + (e&3)
        #pragma unroll
        for (int r = 0; r < 4; ++r) {
            float w0 = __expf(st0[r] * 0.125f) * m0[r];
            float w1 = __expf(st1[r] * 0.125f) * m1[r];
            lsum += w0 + w1;
            pf[r]     = (short)f2bf(w0);
            pf[4 + r] = (short)f2bf(w1);
        }

        #pragma unroll
        for (int dt = 0; dt < 4; ++dt) {
            bf16x8 vf = *(const bf16x8*)(Vtb + (size_t)(dt * 16 + j) * S_LEN + kb + g * 8);
            acc[dt] = __builtin_amdgcn_mfma_f32_16x16x32_bf16(vf, pf, acc[dt], 0, 0, 0);
        }
    }

    // partial lsum over lane groups
    lsum += __shfl_xor(lsum, 16, 64);
    lsum += __shfl_xor(lsum, 32, 64);
    if (g == 0) Plsum[(size_t)sp * NROWS + row] = lsum;

    float* pr = Pacc + ((size_t)sp * NROWS + row) * DMODEL;
    #pragma unroll
    for (int dt = 0; dt < 4; ++dt)
        *(f32x4*)(pr + dt * 16 + g * 4) = acc[dt];
}

// ---- reduce: O = sum_s acc_s / sum_s lsum_s ----
__global__ __launch_bounds__(256)
void reduce_split(const float* __restrict__ Pacc, const float* __restrict__ Plsum,
                  float* __restrict__ O) {
    const int t   = threadIdx.x;
    const size_t rid = (size_t)blockIdx.x * 16 + (t >> 4);
    const int seg = (t & 15) * 4;

    float ls = 0.f;
    f32x4 a = {0.f, 0.f, 0.f, 0.f};
    #pragma unroll
    for (int s = 0; s < NSPLIT; ++s) {
        ls += Plsum[(size_t)s * NROWS + rid];
        f32x4 v = *(const f32x4*)(Pacc + ((size_t)s * NROWS + rid) * DMODEL + seg);
        a[0] += v[0]; a[1] += v[1]; a[2] += v[2]; a[3] += v[3];
    }
    const float inv = 1.0f / ls;
    f32x4 o = {a[0] * inv, a[1] * inv, a[2] * inv, a[3] * inv};
    *(f32x4*)(O + rid * DMODEL + seg) = o;
}

// ---- no-split path (round-6): used when ws too small for partials ----
template <bool WS>
__global__ __launch_bounds__(256)
void attn_v6(const float* __restrict__ Q,
             const float* __restrict__ Kf,
             const float* __restrict__ Vf,
             const unsigned short* __restrict__ Kw,
             const unsigned short* __restrict__ Vta,
             const float* __restrict__ M,
             float* __restrict__ O) {
    const int tid  = threadIdx.x;
    const int wave = tid >> 6;
    const int lane = tid & 63;
    const int g    = lane >> 4;
    const int j    = lane & 15;

    const int bid  = blockIdx.x;
    const int b    = bid & 7;
    const int qt   = bid >> 3;
    const int qrow = qt * QBLK + wave * 16 + j;

    const float* Qb = Q + (size_t)b * S_LEN * DMODEL;
    const bf16x8 qf0 = cvt8(Qb + (size_t)qrow * DMODEL + g * 8);
    const bf16x8 qf1 = cvt8(Qb + (size_t)qrow * DMODEL + g * 8 + 32);

    f32x4 acc[4];
    #pragma unroll
    for (int dt = 0; dt < 4; ++dt) acc[dt] = f32x4{0.f, 0.f, 0.f, 0.f};
    float lsum = 0.f;

    const unsigned short* Kb  = Kw  + (size_t)b * S_LEN * DMODEL;
    const unsigned short* Vtb = Vta + (size_t)b * DMODEL * S_LEN;
    const float* Kfb = Kf + (size_t)b * S_LEN * DMODEL;
    const float* Vfb = Vf + (size_t)b * S_LEN * DMODEL;
    const float* mrow = M + (size_t)qrow * S_LEN;

    int kg[8];
    #pragma unroll
    for (int e = 0; e < 8; ++e) kg[e] = 16 * (e >> 2) + 4 * g + (e & 3);

    #pragma unroll 2
    for (int kt = 0; kt < NKT; ++kt) {
        const int kb = kt * KBLK;

        bf16x8 kf00, kf01, kf10, kf11;
        if (WS) {
            kf00 = *(const bf16x8*)(Kb + (size_t)(kb + j) * DMODEL + g * 8);
            kf01 = *(const bf16x8*)(Kb + (size_t)(kb + j) * DMODEL + g * 8 + 32);
            kf10 = *(const bf16x8*)(Kb + (size_t)(kb + 16 + j) * DMODEL + g * 8);
            kf11 = *(const bf16x8*)(Kb + (size_t)(kb + 16 + j) * DMODEL + g * 8 + 32);
        } else {
            kf00 = cvt8(Kfb + (size_t)(kb + j) * DMODEL + g * 8);
            kf01 = cvt8(Kfb + (size_t)(kb + j) * DMODEL + g * 8 + 32);
            kf10 = cvt8(Kfb + (size_t)(kb + 16 + j) * DMODEL + g * 8);
            kf11 = cvt8(Kfb + (size_t)(kb + 16 + j) * DMODEL + g * 8 + 32);
        }

        f32x4 st0 = {0.f, 0.f, 0.f, 0.f};
        f32x4 st1 = {0.f, 0.f, 0.f, 0.f};
        st0 = __builtin_amdgcn_mfma_f32_16x16x32_bf16(kf00, qf0, st0, 0, 0, 0);
        st0 = __builtin_amdgcn_mfma_f32_16x16x32_bf16(kf01, qf1, st0, 0, 0, 0);
        st1 = __builtin_amdgcn_mfma_f32_16x16x32_bf16(kf10, qf0, st1, 0, 0, 0);
        st1 = __builtin_amdgcn_mfma_f32_16x16x32_bf16(kf11, qf1, st1, 0, 0, 0);

        f32x4 m0 = *(const f32x4*)(mrow + kb + g * 4);
        f32x4 m1 = *(const f32x4*)(mrow + kb + 16 + g * 4);

        bf16x8 pf;
        #pragma unroll
        for (int r = 0; r < 4; ++r) {
            float w0 = __expf(st0[r] * 0.125f) * m0[r];
            float w1 = __expf(st1[r] * 0.125f) * m1[r];
            lsum += w0 + w1;
            pf[r]     = (short)f2bf(w0);
            pf[4 + r] = (short)f2bf(w1);
        }

        #pragma unroll
        for (int dt = 0; dt < 4; ++dt) {
            bf16x8 vf;
            if (WS) {
                vf = *(const bf16x8*)(Vtb + (size_t)(dt * 16 + j) * S_LEN + kb + g * 8);
            } else {
                #pragma unroll
                for (int e = 0; e < 8; ++e)
                    vf[e] = (short)f2bf(Vfb[(size_t)(kb + kg[e]) * DMODEL + dt * 16 + j]);
            }
            acc[dt] = __builtin_amdgcn_mfma_f32_16x16x32_bf16(vf, pf, acc[dt], 0, 0, 0);
        }
    }

    lsum += __shfl_xor(lsum, 16, 64);
    lsum += __shfl_xor(lsum, 32, 64);
    const float inv = 1.0f / lsum;

    float* orow = O + ((size_t)b * S_LEN + qrow) * DMODEL;
    #pragma unroll
    for (int dt = 0; dt < 4; ++dt) {
        f32x4 o;
        #pragma unroll
        for (int r = 0; r < 4; ++r) o[r] = acc[dt][r] * inv;
        *(f32x4*)(orow + dt * 16 + g * 4) = o;
    }
}

extern "C" void kernel_launch(void* const* d_in, const int* in_sizes, int n_in,
                              void* d_out, int out_size, void* d_ws, size_t ws_size,
                              hipStream_t stream) {
    const float* Q = (const float*)d_in[0];
    const float* K = (const float*)d_in[1];
    const float* V = (const float*)d_in[2];
    const float* M = (const float*)d_in[3];
    float* O = (float*)d_out;

    const size_t bytes_kv   = 2 * NELEM * sizeof(unsigned short);            // 8 MB
    const size_t bytes_lsum = (size_t)NSPLIT * NROWS * sizeof(float);        // 0.5 MB
    const size_t bytes_acc  = (size_t)NSPLIT * NROWS * DMODEL * sizeof(float); // 33.5 MB
    const size_t need_split = bytes_kv + bytes_lsum + bytes_acc;
    const size_t need_ws    = bytes_kv;

    if (ws_size >= need_split) {
        unsigned short* Kw  = (unsigned short*)d_ws;
        unsigned short* Vta = Kw + NELEM;
        float* Plsum = (float*)((char*)d_ws + bytes_kv);
        float* Pacc  = Plsum + NSPLIT * NROWS;
        convert_k<<<1024, 256, 0, stream>>>(K, Kw, (int)(NELEM / 4));
        convert_v<<<512, 256, 0, stream>>>(V, Vta);
        attn_split<<<512 * NSPLIT, 256, 0, stream>>>(Q, Kw, Vta, M, Pacc, Plsum);
        reduce_split<<<(int)(NROWS / 16), 256, 0, stream>>>(Pacc, Plsum, O);
    } else if (ws_size >= need_ws) {
        unsigned short* Kw  = (unsigned short*)d_ws;
        unsigned short* Vta = Kw + NELEM;
        convert_k<<<1024, 256, 0, stream>>>(K, Kw, (int)(NELEM / 4));
        convert_v<<<512, 256, 0, stream>>>(V, Vta);
        attn_v6<true><<<512, 256, 0, stream>>>(Q, K, V, Kw, Vta, M, O);
    } else {
        attn_v6<false><<<512, 256, 0, stream>>>(Q, K, V, nullptr, nullptr, M, O);
    }
}

// Round 8
// 115.159 us; speedup vs baseline: 2.6614x; 2.6614x over previous
//
#include <hip/hip_runtime.h>

#define S_LEN 4096
#define DMODEL 64
#define QBLK 64
#define KBLK 32
#define NKT (S_LEN / KBLK)                  // 128 k-tiles
#define NSPLIT 4
#define NROWS ((size_t)8 * S_LEN)           // 32768 (b,q) rows
#define NELEM ((size_t)8 * S_LEN * DMODEL)  // per-tensor elements (Q/K/V)
#define TSZ 2048                            // elements per 32-key tile

typedef __attribute__((ext_vector_type(8))) short bf16x8;
typedef __attribute__((ext_vector_type(4))) float f32x4;
typedef __attribute__((ext_vector_type(4))) unsigned short us4;
typedef __attribute__((ext_vector_type(8))) unsigned short us8;

__device__ __forceinline__ float bf2f(unsigned short u) {
    unsigned int x = ((unsigned int)u) << 16;
    return __builtin_bit_cast(float, x);
}
__device__ __forceinline__ unsigned short f2bf(float f) {
    unsigned int u = __builtin_bit_cast(unsigned int, f);
    u += 0x7FFFu + ((u >> 16) & 1u);   // RNE
    return (unsigned short)(u >> 16);
}
__device__ __forceinline__ bf16x8 cvt8(const float* __restrict__ p) {
    f32x4 a = *(const f32x4*)p;
    f32x4 b = *(const f32x4*)(p + 4);
    bf16x8 r;
    r[0] = (short)f2bf(a[0]); r[1] = (short)f2bf(a[1]);
    r[2] = (short)f2bf(a[2]); r[3] = (short)f2bf(a[3]);
    r[4] = (short)f2bf(b[0]); r[5] = (short)f2bf(b[1]);
    r[6] = (short)f2bf(b[2]); r[7] = (short)f2bf(b[3]);
    return r;
}

// ---- K: fp32 -> bf16, row-major (each 32-key tile is a contiguous 4KB block) ----
__global__ __launch_bounds__(256)
void convert_k(const float* __restrict__ src, unsigned short* __restrict__ dst, int n4) {
    int i = blockIdx.x * blockDim.x + threadIdx.x;
    const int stride = gridDim.x * blockDim.x;
    for (; i < n4; i += stride) {
        f32x4 v = ((const f32x4*)src)[i];
        us4 o;
        o[0] = f2bf(v[0]); o[1] = f2bf(v[1]); o[2] = f2bf(v[2]); o[3] = f2bf(v[3]);
        ((us4*)dst)[i] = o;
    }
}

// ---- V: fp32 [b][k][d] -> bf16 tiles Vtt[b][kt][d][pos], pos=g*8+hi*4+r holds
//      key 16*hi+4*g+r, so a bf16x8 at [d][g*8] is exactly the PV A-fragment ----
__global__ __launch_bounds__(256)
void convert_v(const float* __restrict__ V, unsigned short* __restrict__ Vtt) {
    __shared__ unsigned short lk[KBLK][68];
    const int t  = threadIdx.x;
    const int b  = blockIdx.x >> 7;
    const int kt = blockIdx.x & 127;
    {
        const int key = t >> 3, d0 = (t & 7) * 8;
        const float* src = V + ((size_t)b * S_LEN + kt * KBLK + key) * DMODEL + d0;
        f32x4 a = *(const f32x4*)src;
        f32x4 c = *(const f32x4*)(src + 4);
        lk[key][d0 + 0] = f2bf(a[0]); lk[key][d0 + 1] = f2bf(a[1]);
        lk[key][d0 + 2] = f2bf(a[2]); lk[key][d0 + 3] = f2bf(a[3]);
        lk[key][d0 + 4] = f2bf(c[0]); lk[key][d0 + 5] = f2bf(c[1]);
        lk[key][d0 + 6] = f2bf(c[2]); lk[key][d0 + 7] = f2bf(c[3]);
    }
    __syncthreads();
    {
        const int d = t >> 2, g = t & 3;
        us8 o;
        #pragma unroll
        for (int e = 0; e < 8; ++e) {
            const int key = 16 * (e >> 2) + 4 * g + (e & 3);
            o[e] = lk[key][d];
        }
        *(us8*)(Vtt + ((size_t)b * NKT + kt) * TSZ + d * 32 + g * 8) = o;
    }
}

// ---- mask: fp32 [q][k] -> bf16 tiles Mt[qt][kt][row][pos] (same pos->key map) ----
__global__ __launch_bounds__(256)
void convert_m(const float* __restrict__ M, unsigned short* __restrict__ Mt) {
    const int t   = threadIdx.x;
    const int qt  = blockIdx.x >> 7;
    const int kt  = blockIdx.x & 127;
    const int row = t >> 2, g = t & 3;
    const float* src = M + ((size_t)qt * QBLK + row) * S_LEN + kt * KBLK;
    f32x4 a = *(const f32x4*)(src + 4 * g);
    f32x4 c = *(const f32x4*)(src + 16 + 4 * g);
    us8 o;
    o[0] = f2bf(a[0]); o[1] = f2bf(a[1]); o[2] = f2bf(a[2]); o[3] = f2bf(a[3]);
    o[4] = f2bf(c[0]); o[5] = f2bf(c[1]); o[6] = f2bf(c[2]); o[7] = f2bf(c[3]);
    *(us8*)(Mt + ((size_t)qt * NKT + kt) * TSZ + row * 32 + g * 8) = o;
}

// ---- staged attention: LDS K/V tiles, T14 prefetch, optional split-K ----
template <bool MT, int SPLITS>
__global__ __launch_bounds__(256)
void attn_staged(const float* __restrict__ Q,
                 const unsigned short* __restrict__ Kw,
                 const unsigned short* __restrict__ Vtt,
                 const unsigned short* __restrict__ Mt,
                 const float* __restrict__ Mf,
                 float* __restrict__ Pacc, float* __restrict__ Plsum,
                 float* __restrict__ O) {
    __shared__ __align__(16) unsigned short K_lds[KBLK][72];   // 16B-aligned rows, spread banks
    __shared__ __align__(16) unsigned short V_lds[DMODEL][40];

    const int t    = threadIdx.x;
    const int wave = t >> 6;
    const int lane = t & 63;
    const int g    = lane >> 4;
    const int j    = lane & 15;

    const int bid = blockIdx.x;
    const int b   = bid & 7;             // batch <-> XCD co-location (K/V ~1MB -> L2-resident)
    const int qt  = (bid >> 3) & 63;
    const int sp  = (SPLITS > 1) ? (bid >> 9) : 0;
    const int nsteps = NKT / SPLITS;
    const int qrow = qt * QBLK + wave * 16 + j;
    const size_t row = (size_t)b * S_LEN + qrow;

    const float* Qb = Q + (size_t)b * S_LEN * DMODEL;
    const bf16x8 qf0 = cvt8(Qb + (size_t)qrow * DMODEL + g * 8);
    const bf16x8 qf1 = cvt8(Qb + (size_t)qrow * DMODEL + g * 8 + 32);

    f32x4 acc[4];
    #pragma unroll
    for (int dt = 0; dt < 4; ++dt) acc[dt] = f32x4{0.f, 0.f, 0.f, 0.f};
    float lsum = 0.f;

    const unsigned short* Kb  = Kw  + (size_t)b * S_LEN * DMODEL;
    const unsigned short* Vb  = Vtt + (size_t)b * NKT * TSZ;
    const unsigned short* Mtl = Mt + (size_t)qt * NKT * TSZ + (size_t)(wave * 16 + j) * 32 + g * 8;
    const float* mrow = Mf + (size_t)qrow * S_LEN;

    int kt = sp * nsteps;

    // prologue: prefetch tile kt into regs
    us8 kreg = *(const us8*)(Kb + (size_t)kt * TSZ + t * 8);
    us8 vreg = *(const us8*)(Vb + (size_t)kt * TSZ + t * 8);
    us8 mreg{};
    f32x4 mra{}, mrc{};
    if (MT) mreg = *(const us8*)(Mtl + (size_t)kt * TSZ);
    else {
        mra = *(const f32x4*)(mrow + kt * KBLK + g * 4);
        mrc = *(const f32x4*)(mrow + kt * KBLK + 16 + g * 4);
    }

    for (int s = 0; s < nsteps; ++s, ++kt) {
        __syncthreads();   // previous step's LDS reads done
        *(us8*)&K_lds[t >> 3][(t & 7) * 8] = kreg;
        *(us8*)&V_lds[t >> 2][(t & 3) * 8] = vreg;
        const us8 mcur = mreg;
        const f32x4 ma = mra, mc = mrc;
        if (s + 1 < nsteps) {   // T14: issue next-tile loads; latency hides under compute
            kreg = *(const us8*)(Kb + (size_t)(kt + 1) * TSZ + t * 8);
            vreg = *(const us8*)(Vb + (size_t)(kt + 1) * TSZ + t * 8);
            if (MT) mreg = *(const us8*)(Mtl + (size_t)(kt + 1) * TSZ);
            else {
                mra = *(const f32x4*)(mrow + (kt + 1) * KBLK + g * 4);
                mrc = *(const f32x4*)(mrow + (kt + 1) * KBLK + 16 + g * 4);
            }
        }
        __syncthreads();   // staging visible

        // ---- S^T = K * Q^T from LDS ----
        bf16x8 kf00 = *(const bf16x8*)&K_lds[j][g * 8];
        bf16x8 kf01 = *(const bf16x8*)&K_lds[j][32 + g * 8];
        bf16x8 kf10 = *(const bf16x8*)&K_lds[16 + j][g * 8];
        bf16x8 kf11 = *(const bf16x8*)&K_lds[16 + j][32 + g * 8];

        f32x4 st0 = {0.f, 0.f, 0.f, 0.f};
        f32x4 st1 = {0.f, 0.f, 0.f, 0.f};
        st0 = __builtin_amdgcn_mfma_f32_16x16x32_bf16(kf00, qf0, st0, 0, 0, 0);
        st0 = __builtin_amdgcn_mfma_f32_16x16x32_bf16(kf01, qf1, st0, 0, 0, 0);
        st1 = __builtin_amdgcn_mfma_f32_16x16x32_bf16(kf10, qf0, st1, 0, 0, 0);
        st1 = __builtin_amdgcn_mfma_f32_16x16x32_bf16(kf11, qf1, st1, 0, 0, 0);
        // st0[r]: key kb+4g+r, st1[r]: key kb+16+4g+r, column q = qrow

        float m0[4], m1[4];
        #pragma unroll
        for (int r = 0; r < 4; ++r) {
            if (MT) { m0[r] = bf2f(mcur[r]); m1[r] = bf2f(mcur[4 + r]); }
            else    { m0[r] = ma[r];          m1[r] = mc[r]; }
        }

        bf16x8 pf;   // slot e holds key kb + 16*(e>>2) + 4g + (e&3)
        #pragma unroll
        for (int r = 0; r < 4; ++r) {
            float w0 = __expf(st0[r] * 0.125f) * m0[r];
            float w1 = __expf(st1[r] * 0.125f) * m1[r];
            lsum += w0 + w1;
            pf[r]     = (short)f2bf(w0);
            pf[4 + r] = (short)f2bf(w1);
        }

        #pragma unroll
        for (int dt = 0; dt < 4; ++dt) {
            bf16x8 vf = *(const bf16x8*)&V_lds[dt * 16 + j][g * 8];
            acc[dt] = __builtin_amdgcn_mfma_f32_16x16x32_bf16(vf, pf, acc[dt], 0, 0, 0);
        }
    }

    lsum += __shfl_xor(lsum, 16, 64);
    lsum += __shfl_xor(lsum, 32, 64);

    if (SPLITS > 1) {
        if (g == 0) Plsum[(size_t)sp * NROWS + row] = lsum;
        float* pr = Pacc + ((size_t)sp * NROWS + row) * DMODEL;
        #pragma unroll
        for (int dt = 0; dt < 4; ++dt)
            *(f32x4*)(pr + dt * 16 + g * 4) = acc[dt];
    } else {
        const float inv = 1.0f / lsum;
        float* orow = O + row * DMODEL;
        #pragma unroll
        for (int dt = 0; dt < 4; ++dt) {
            f32x4 o;
            #pragma unroll
            for (int r = 0; r < 4; ++r) o[r] = acc[dt][r] * inv;
            *(f32x4*)(orow + dt * 16 + g * 4) = o;
        }
    }
}

// ---- reduce: O = sum_s acc_s / sum_s lsum_s ----
__global__ __launch_bounds__(256)
void reduce_split(const float* __restrict__ Pacc, const float* __restrict__ Plsum,
                  float* __restrict__ O) {
    const int t = threadIdx.x;
    const size_t rid = (size_t)blockIdx.x * 16 + (t >> 4);
    const int seg = (t & 15) * 4;

    float ls = 0.f;
    f32x4 a = {0.f, 0.f, 0.f, 0.f};
    #pragma unroll
    for (int s = 0; s < NSPLIT; ++s) {
        ls += Plsum[(size_t)s * NROWS + rid];
        f32x4 v = *(const f32x4*)(Pacc + ((size_t)s * NROWS + rid) * DMODEL + seg);
        a[0] += v[0]; a[1] += v[1]; a[2] += v[2]; a[3] += v[3];
    }
    const float inv = 1.0f / ls;
    f32x4 o = {a[0] * inv, a[1] * inv, a[2] * inv, a[3] * inv};
    *(f32x4*)(O + rid * DMODEL + seg) = o;
}

// ---- no-workspace fallback: direct fp32 loads, scalar V gather ----
__global__ __launch_bounds__(256)
void attn_fb(const float* __restrict__ Q, const float* __restrict__ Kf,
             const float* __restrict__ Vf, const float* __restrict__ M,
             float* __restrict__ O) {
    const int t    = threadIdx.x;
    const int wave = t >> 6;
    const int lane = t & 63;
    const int g    = lane >> 4;
    const int j    = lane & 15;
    const int bid  = blockIdx.x;
    const int b    = bid & 7;
    const int qt   = bid >> 3;
    const int qrow = qt * QBLK + wave * 16 + j;

    const float* Qb = Q + (size_t)b * S_LEN * DMODEL;
    const bf16x8 qf0 = cvt8(Qb + (size_t)qrow * DMODEL + g * 8);
    const bf16x8 qf1 = cvt8(Qb + (size_t)qrow * DMODEL + g * 8 + 32);

    f32x4 acc[4];
    #pragma unroll
    for (int dt = 0; dt < 4; ++dt) acc[dt] = f32x4{0.f, 0.f, 0.f, 0.f};
    float lsum = 0.f;

    const float* Kfb = Kf + (size_t)b * S_LEN * DMODEL;
    const float* Vfb = Vf + (size_t)b * S_LEN * DMODEL;
    const float* mrow = M + (size_t)qrow * S_LEN;

    int kg[8];
    #pragma unroll
    for (int e = 0; e < 8; ++e) kg[e] = 16 * (e >> 2) + 4 * g + (e & 3);

    for (int kt = 0; kt < NKT; ++kt) {
        const int kb = kt * KBLK;
        bf16x8 kf00 = cvt8(Kfb + (size_t)(kb + j) * DMODEL + g * 8);
        bf16x8 kf01 = cvt8(Kfb + (size_t)(kb + j) * DMODEL + g * 8 + 32);
        bf16x8 kf10 = cvt8(Kfb + (size_t)(kb + 16 + j) * DMODEL + g * 8);
        bf16x8 kf11 = cvt8(Kfb + (size_t)(kb + 16 + j) * DMODEL + g * 8 + 32);

        f32x4 st0 = {0.f, 0.f, 0.f, 0.f};
        f32x4 st1 = {0.f, 0.f, 0.f, 0.f};
        st0 = __builtin_amdgcn_mfma_f32_16x16x32_bf16(kf00, qf0, st0, 0, 0, 0);
        st0 = __builtin_amdgcn_mfma_f32_16x16x32_bf16(kf01, qf1, st0, 0, 0, 0);
        st1 = __builtin_amdgcn_mfma_f32_16x16x32_bf16(kf10, qf0, st1, 0, 0, 0);
        st1 = __builtin_amdgcn_mfma_f32_16x16x32_bf16(kf11, qf1, st1, 0, 0, 0);

        f32x4 m0 = *(const f32x4*)(mrow + kb + g * 4);
        f32x4 m1 = *(const f32x4*)(mrow + kb + 16 + g * 4);

        bf16x8 pf;
        #pragma unroll
        for (int r = 0; r < 4; ++r) {
            float w0 = __expf(st0[r] * 0.125f) * m0[r];
            float w1 = __expf(st1[r] * 0.125f) * m1[r];
            lsum += w0 + w1;
            pf[r]     = (short)f2bf(w0);
            pf[4 + r] = (short)f2bf(w1);
        }

        #pragma unroll
        for (int dt = 0; dt < 4; ++dt) {
            bf16x8 vf;
            #pragma unroll
            for (int e = 0; e < 8; ++e)
                vf[e] = (short)f2bf(Vfb[(size_t)(kb + kg[e]) * DMODEL + dt * 16 + j]);
            acc[dt] = __builtin_amdgcn_mfma_f32_16x16x32_bf16(vf, pf, acc[dt], 0, 0, 0);
        }
    }

    lsum += __shfl_xor(lsum, 16, 64);
    lsum += __shfl_xor(lsum, 32, 64);
    const float inv = 1.0f / lsum;

    float* orow = O + ((size_t)b * S_LEN + qrow) * DMODEL;
    #pragma unroll
    for (int dt = 0; dt < 4; ++dt) {
        f32x4 o;
        #pragma unroll
        for (int r = 0; r < 4; ++r) o[r] = acc[dt][r] * inv;
        *(f32x4*)(orow + dt * 16 + g * 4) = o;
    }
}

extern "C" void kernel_launch(void* const* d_in, const int* in_sizes, int n_in,
                              void* d_out, int out_size, void* d_ws, size_t ws_size,
                              hipStream_t stream) {
    const float* Q = (const float*)d_in[0];
    const float* K = (const float*)d_in[1];
    const float* V = (const float*)d_in[2];
    const float* M = (const float*)d_in[3];
    float* O = (float*)d_out;

    const size_t bytes_k  = NELEM * 2;                                // 4 MB
    const size_t bytes_v  = NELEM * 2;                                // 4 MB
    const size_t bytes_m  = (size_t)S_LEN * S_LEN * 2;                // 32 MB
    const size_t bytes_ls = (size_t)NSPLIT * NROWS * 4;               // 0.5 MB
    const size_t bytes_pa = (size_t)NSPLIT * NROWS * DMODEL * 4;      // 33.5 MB

    const size_t need_kv   = bytes_k + bytes_v;                       //  8 MB
    const size_t need_mt   = need_kv + bytes_m;                       // 40 MB
    const size_t need_full = need_mt + bytes_ls + bytes_pa;           // 74 MB

    unsigned short* Kw  = (unsigned short*)d_ws;
    unsigned short* Vtt = Kw + NELEM;
    unsigned short* Mt  = Vtt + NELEM;
    float* Plsum = (float*)((char*)d_ws + need_mt);
    float* Pacc  = Plsum + NSPLIT * NROWS;

    if (ws_size >= need_full) {
        convert_k<<<1024, 256, 0, stream>>>(K, Kw, (int)(NELEM / 4));
        convert_v<<<1024, 256, 0, stream>>>(V, Vtt);
        convert_m<<<64 * 128, 256, 0, stream>>>(M, Mt);
        attn_staged<true, NSPLIT><<<512 * NSPLIT, 256, 0, stream>>>(
            Q, Kw, Vtt, Mt, M, Pacc, Plsum, O);
        reduce_split<<<(int)(NROWS / 16), 256, 0, stream>>>(Pacc, Plsum, O);
    } else if (ws_size >= need_mt) {
        convert_k<<<1024, 256, 0, stream>>>(K, Kw, (int)(NELEM / 4));
        convert_v<<<1024, 256, 0, stream>>>(V, Vtt);
        convert_m<<<64 * 128, 256, 0, stream>>>(M, Mt);
        attn_staged<true, 1><<<512, 256, 0, stream>>>(
            Q, Kw, Vtt, Mt, M, nullptr, nullptr, O);
    } else if (ws_size >= need_kv) {
        convert_k<<<1024, 256, 0, stream>>>(K, Kw, (int)(NELEM / 4));
        convert_v<<<1024, 256, 0, stream>>>(V, Vtt);
        attn_staged<false, 1><<<512, 256, 0, stream>>>(
            Q, Kw, Vtt, nullptr, M, nullptr, nullptr, O);
    } else {
        attn_fb<<<512, 256, 0, stream>>>(Q, K, V, M, O);
    }
}

// Round 10
// 114.719 us; speedup vs baseline: 2.6716x; 1.0038x over previous
//
#include <hip/hip_runtime.h>

#define S_LEN 4096
#define DMODEL 64
#define QBLK 64
#define KBLK 32
#define NKT (S_LEN / KBLK)                  // 128 k-tiles
#define NSPLIT 4
#define NROWS ((size_t)8 * S_LEN)           // 32768 (b,q) rows
#define NELEM ((size_t)8 * S_LEN * DMODEL)  // per-tensor elements (Q/K/V)
#define TSZ 2048                            // elements per 32-key tile
#define QSCALE 0.180336880f                 // 0.125 * log2(e): folds 1/sqrt(64) and exp->exp2

typedef __attribute__((ext_vector_type(8))) short bf16x8;
typedef __attribute__((ext_vector_type(4))) float f32x4;
typedef __attribute__((ext_vector_type(4))) unsigned short us4;
typedef __attribute__((ext_vector_type(8))) unsigned short us8;
typedef __attribute__((ext_vector_type(4))) unsigned int u32x4;

__device__ __forceinline__ unsigned short f2bf(float f) {
    unsigned int u = __builtin_bit_cast(unsigned int, f);
    u += 0x7FFFu + ((u >> 16) & 1u);   // RNE
    return (unsigned short)(u >> 16);
}
// pack two floats into one u32 of 2xbf16 (lo, hi)
__device__ __forceinline__ unsigned int pack2bf(float lo, float hi) {
    return (unsigned int)f2bf(lo) | ((unsigned int)f2bf(hi) << 16);
}
// load 8 fp32, scale, convert to bf16 fragment
__device__ __forceinline__ bf16x8 cvt8s(const float* __restrict__ p, float c) {
    f32x4 a = *(const f32x4*)p;
    f32x4 b = *(const f32x4*)(p + 4);
    bf16x8 r;
    r[0] = (short)f2bf(a[0] * c); r[1] = (short)f2bf(a[1] * c);
    r[2] = (short)f2bf(a[2] * c); r[3] = (short)f2bf(a[3] * c);
    r[4] = (short)f2bf(b[0] * c); r[5] = (short)f2bf(b[1] * c);
    r[6] = (short)f2bf(b[2] * c); r[7] = (short)f2bf(b[3] * c);
    return r;
}

// ---- K: fp32 -> bf16, row-major (each 32-key tile is a contiguous 4KB block) ----
__global__ __launch_bounds__(256)
void convert_k(const float* __restrict__ src, unsigned short* __restrict__ dst, int n4) {
    int i = blockIdx.x * blockDim.x + threadIdx.x;
    const int stride = gridDim.x * blockDim.x;
    for (; i < n4; i += stride) {
        f32x4 v = ((const f32x4*)src)[i];
        us4 o;
        o[0] = f2bf(v[0]); o[1] = f2bf(v[1]); o[2] = f2bf(v[2]); o[3] = f2bf(v[3]);
        ((us4*)dst)[i] = o;
    }
}

// ---- V: fp32 [b][k][d] -> bf16 tiles Vtt[b][kt][d][pos], pos=g*8+hi*4+r holds
//      key 16*hi+4*g+r, so a bf16x8 at [d][g*8] is exactly the PV A-fragment ----
__global__ __launch_bounds__(256)
void convert_v(const float* __restrict__ V, unsigned short* __restrict__ Vtt) {
    __shared__ unsigned short lk[KBLK][68];
    const int t  = threadIdx.x;
    const int b  = blockIdx.x >> 7;
    const int kt = blockIdx.x & 127;
    {
        const int key = t >> 3, d0 = (t & 7) * 8;
        const float* src = V + ((size_t)b * S_LEN + kt * KBLK + key) * DMODEL + d0;
        f32x4 a = *(const f32x4*)src;
        f32x4 c = *(const f32x4*)(src + 4);
        lk[key][d0 + 0] = f2bf(a[0]); lk[key][d0 + 1] = f2bf(a[1]);
        lk[key][d0 + 2] = f2bf(a[2]); lk[key][d0 + 3] = f2bf(a[3]);
        lk[key][d0 + 4] = f2bf(c[0]); lk[key][d0 + 5] = f2bf(c[1]);
        lk[key][d0 + 6] = f2bf(c[2]); lk[key][d0 + 7] = f2bf(c[3]);
    }
    __syncthreads();
    {
        const int d = t >> 2, g = t & 3;
        us8 o;
        #pragma unroll
        for (int e = 0; e < 8; ++e) {
            const int key = 16 * (e >> 2) + 4 * g + (e & 3);
            o[e] = lk[key][d];
        }
        *(us8*)(Vtt + ((size_t)b * NKT + kt) * TSZ + d * 32 + g * 8) = o;
    }
}

// ---- staged attention: LDS K/V tiles, T14 prefetch, fp32 mask direct, MFMA lsum ----
template <int SPLITS>
__global__ __launch_bounds__(256)
void attn_staged(const float* __restrict__ Q,
                 const unsigned short* __restrict__ Kw,
                 const unsigned short* __restrict__ Vtt,
                 const float* __restrict__ Mf,
                 float* __restrict__ Pacc, float* __restrict__ Plsum,
                 float* __restrict__ O) {
    __shared__ __align__(16) unsigned short K_lds[KBLK][72];    // 144B rows (16B-aligned)
    __shared__ __align__(16) unsigned short V_lds[DMODEL][40];  // 80B rows (16B-aligned)

    const int t    = threadIdx.x;
    const int wave = t >> 6;
    const int lane = t & 63;
    const int g    = lane >> 4;
    const int j    = lane & 15;

    const int bid = blockIdx.x;
    const int b   = bid & 7;             // batch <-> XCD co-location (K/V L2-resident)
    const int qt  = (bid >> 3) & 63;
    const int sp  = (SPLITS > 1) ? (bid >> 9) : 0;
    const int nsteps = NKT / SPLITS;
    const int qrow = qt * QBLK + wave * 16 + j;
    const size_t row = (size_t)b * S_LEN + qrow;

    const float* Qb = Q + (size_t)b * S_LEN * DMODEL;
    // Q pre-scaled: scores come out as s*0.125*log2e -> feed exp2 directly
    const bf16x8 qf0 = cvt8s(Qb + (size_t)qrow * DMODEL + g * 8, QSCALE);
    const bf16x8 qf1 = cvt8s(Qb + (size_t)qrow * DMODEL + g * 8 + 32, QSCALE);

    bf16x8 vones;
    #pragma unroll
    for (int e = 0; e < 8; ++e) vones[e] = (short)0x3F80;   // bf16 1.0

    f32x4 acc[4];
    #pragma unroll
    for (int dt = 0; dt < 4; ++dt) acc[dt] = f32x4{0.f, 0.f, 0.f, 0.f};
    f32x4 accl = {0.f, 0.f, 0.f, 0.f};   // lsum accumulator (ones^T * P)

    const unsigned short* Kb = Kw  + (size_t)b * S_LEN * DMODEL;
    const unsigned short* Vb = Vtt + (size_t)b * NKT * TSZ;
    const float* mrow = Mf + (size_t)qrow * S_LEN;

    int kt = sp * nsteps;

    // prologue: prefetch tile kt into regs
    us8 kreg = *(const us8*)(Kb + (size_t)kt * TSZ + t * 8);
    us8 vreg = *(const us8*)(Vb + (size_t)kt * TSZ + t * 8);
    f32x4 mra = *(const f32x4*)(mrow + kt * KBLK + g * 4);
    f32x4 mrc = *(const f32x4*)(mrow + kt * KBLK + 16 + g * 4);

    for (int s = 0; s < nsteps; ++s, ++kt) {
        __syncthreads();   // previous step's LDS reads done
        *(us8*)&K_lds[t >> 3][(t & 7) * 8] = kreg;
        *(us8*)&V_lds[t >> 2][(t & 3) * 8] = vreg;
        const f32x4 ma = mra, mc = mrc;
        if (s + 1 < nsteps) {   // T14: next-tile loads fly under this step's compute
            kreg = *(const us8*)(Kb + (size_t)(kt + 1) * TSZ + t * 8);
            vreg = *(const us8*)(Vb + (size_t)(kt + 1) * TSZ + t * 8);
            mra  = *(const f32x4*)(mrow + (kt + 1) * KBLK + g * 4);
            mrc  = *(const f32x4*)(mrow + (kt + 1) * KBLK + 16 + g * 4);
        }
        __syncthreads();   // staging visible

        // ---- S^T = K * Q^T from LDS ----
        bf16x8 kf00 = *(const bf16x8*)&K_lds[j][g * 8];
        bf16x8 kf01 = *(const bf16x8*)&K_lds[j][32 + g * 8];
        bf16x8 kf10 = *(const bf16x8*)&K_lds[16 + j][g * 8];
        bf16x8 kf11 = *(const bf16x8*)&K_lds[16 + j][32 + g * 8];

        f32x4 st0 = {0.f, 0.f, 0.f, 0.f};
        f32x4 st1 = {0.f, 0.f, 0.f, 0.f};
        st0 = __builtin_amdgcn_mfma_f32_16x16x32_bf16(kf00, qf0, st0, 0, 0, 0);
        st0 = __builtin_amdgcn_mfma_f32_16x16x32_bf16(kf01, qf1, st0, 0, 0, 0);
        st1 = __builtin_amdgcn_mfma_f32_16x16x32_bf16(kf10, qf0, st1, 0, 0, 0);
        st1 = __builtin_amdgcn_mfma_f32_16x16x32_bf16(kf11, qf1, st1, 0, 0, 0);
        // st0[r]: key kb+4g+r, st1[r]: key kb+16+4g+r, column q = qrow

        // ---- weights: w = 2^st * mask (scales folded into Q) ----
        float e0[4], e1[4];
        #pragma unroll
        for (int r = 0; r < 4; ++r) {
            e0[r] = __builtin_amdgcn_exp2f(st0[r]) * ma[r];
            e1[r] = __builtin_amdgcn_exp2f(st1[r]) * mc[r];
        }
        u32x4 pw;
        pw[0] = pack2bf(e0[0], e0[1]);
        pw[1] = pack2bf(e0[2], e0[3]);
        pw[2] = pack2bf(e1[0], e1[1]);
        pw[3] = pack2bf(e1[2], e1[3]);
        const bf16x8 pf = __builtin_bit_cast(bf16x8, pw);   // slot e: key kb+16*(e>>2)+4g+(e&3)

        // ---- lsum via matrix pipe: ones^T * P sums ALL 32 keys per column ----
        accl = __builtin_amdgcn_mfma_f32_16x16x32_bf16(vones, pf, accl, 0, 0, 0);

        // ---- O^T += V^T * P ----
        #pragma unroll
        for (int dt = 0; dt < 4; ++dt) {
            bf16x8 vf = *(const bf16x8*)&V_lds[dt * 16 + j][g * 8];
            acc[dt] = __builtin_amdgcn_mfma_f32_16x16x32_bf16(vf, pf, acc[dt], 0, 0, 0);
        }
    }

    const float lsum = accl[0];   // full split-sum, identical in all regs/lane-groups

    if (SPLITS > 1) {
        if (g == 0) Plsum[(size_t)sp * NROWS + row] = lsum;
        float* pr = Pacc + ((size_t)sp * NROWS + row) * DMODEL;
        #pragma unroll
        for (int dt = 0; dt < 4; ++dt)
            *(f32x4*)(pr + dt * 16 + g * 4) = acc[dt];
    } else {
        const float inv = 1.0f / lsum;
        float* orow = O + row * DMODEL;
        #pragma unroll
        for (int dt = 0; dt < 4; ++dt) {
            f32x4 o;
            #pragma unroll
            for (int r = 0; r < 4; ++r) o[r] = acc[dt][r] * inv;
            *(f32x4*)(orow + dt * 16 + g * 4) = o;
        }
    }
}

// ---- reduce: O = sum_s acc_s / sum_s lsum_s ----
__global__ __launch_bounds__(256)
void reduce_split(const float* __restrict__ Pacc, const float* __restrict__ Plsum,
                  float* __restrict__ O) {
    const int t = threadIdx.x;
    const size_t rid = (size_t)blockIdx.x * 16 + (t >> 4);
    const int seg = (t & 15) * 4;

    float ls = 0.f;
    f32x4 a = {0.f, 0.f, 0.f, 0.f};
    #pragma unroll
    for (int s = 0; s < NSPLIT; ++s) {
        ls += Plsum[(size_t)s * NROWS + rid];
        f32x4 v = *(const f32x4*)(Pacc + ((size_t)s * NROWS + rid) * DMODEL + seg);
        a[0] += v[0]; a[1] += v[1]; a[2] += v[2]; a[3] += v[3];
    }
    const float inv = 1.0f / ls;
    f32x4 o = {a[0] * inv, a[1] * inv, a[2] * inv, a[3] * inv};
    *(f32x4*)(O + rid * DMODEL + seg) = o;
}

// ---- no-workspace fallback: direct fp32 loads, scalar V gather ----
__global__ __launch_bounds__(256)
void attn_fb(const float* __restrict__ Q, const float* __restrict__ Kf,
             const float* __restrict__ Vf, const float* __restrict__ M,
             float* __restrict__ O) {
    const int t    = threadIdx.x;
    const int wave = t >> 6;
    const int lane = t & 63;
    const int g    = lane >> 4;
    const int j    = lane & 15;
    const int bid  = blockIdx.x;
    const int b    = bid & 7;
    const int qt   = bid >> 3;
    const int qrow = qt * QBLK + wave * 16 + j;

    const float* Qb = Q + (size_t)b * S_LEN * DMODEL;
    const bf16x8 qf0 = cvt8s(Qb + (size_t)qrow * DMODEL + g * 8, QSCALE);
    const bf16x8 qf1 = cvt8s(Qb + (size_t)qrow * DMODEL + g * 8 + 32, QSCALE);

    f32x4 acc[4];
    #pragma unroll
    for (int dt = 0; dt < 4; ++dt) acc[dt] = f32x4{0.f, 0.f, 0.f, 0.f};
    float lsum = 0.f;

    const float* Kfb = Kf + (size_t)b * S_LEN * DMODEL;
    const float* Vfb = Vf + (size_t)b * S_LEN * DMODEL;
    const float* mrow = M + (size_t)qrow * S_LEN;

    int kg[8];
    #pragma unroll
    for (int e = 0; e < 8; ++e) kg[e] = 16 * (e >> 2) + 4 * g + (e & 3);

    for (int kt = 0; kt < NKT; ++kt) {
        const int kb = kt * KBLK;
        bf16x8 kf00 = cvt8s(Kfb + (size_t)(kb + j) * DMODEL + g * 8, 1.0f);
        bf16x8 kf01 = cvt8s(Kfb + (size_t)(kb + j) * DMODEL + g * 8 + 32, 1.0f);
        bf16x8 kf10 = cvt8s(Kfb + (size_t)(kb + 16 + j) * DMODEL + g * 8, 1.0f);
        bf16x8 kf11 = cvt8s(Kfb + (size_t)(kb + 16 + j) * DMODEL + g * 8 + 32, 1.0f);

        f32x4 st0 = {0.f, 0.f, 0.f, 0.f};
        f32x4 st1 = {0.f, 0.f, 0.f, 0.f};
        st0 = __builtin_amdgcn_mfma_f32_16x16x32_bf16(kf00, qf0, st0, 0, 0, 0);
        st0 = __builtin_amdgcn_mfma_f32_16x16x32_bf16(kf01, qf1, st0, 0, 0, 0);
        st1 = __builtin_amdgcn_mfma_f32_16x16x32_bf16(kf10, qf0, st1, 0, 0, 0);
        st1 = __builtin_amdgcn_mfma_f32_16x16x32_bf16(kf11, qf1, st1, 0, 0, 0);

        f32x4 m0 = *(const f32x4*)(mrow + kb + g * 4);
        f32x4 m1 = *(const f32x4*)(mrow + kb + 16 + g * 4);

        bf16x8 pf;
        #pragma unroll
        for (int r = 0; r < 4; ++r) {
            float w0 = __builtin_amdgcn_exp2f(st0[r]) * m0[r];
            float w1 = __builtin_amdgcn_exp2f(st1[r]) * m1[r];
            lsum += w0 + w1;
            pf[r]     = (short)f2bf(w0);
            pf[4 + r] = (short)f2bf(w1);
        }

        #pragma unroll
        for (int dt = 0; dt < 4; ++dt) {
            bf16x8 vf;
            #pragma unroll
            for (int e = 0; e < 8; ++e)
                vf[e] = (short)f2bf(Vfb[(size_t)(kb + kg[e]) * DMODEL + dt * 16 + j]);
            acc[dt] = __builtin_amdgcn_mfma_f32_16x16x32_bf16(vf, pf, acc[dt], 0, 0, 0);
        }
    }

    lsum += __shfl_xor(lsum, 16, 64);
    lsum += __shfl_xor(lsum, 32, 64);
    const float inv = 1.0f / lsum;

    float* orow = O + ((size_t)b * S_LEN + qrow) * DMODEL;
    #pragma unroll
    for (int dt = 0; dt < 4; ++dt) {
        f32x4 o;
        #pragma unroll
        for (int r = 0; r < 4; ++r) o[r] = acc[dt][r] * inv;
        *(f32x4*)(orow + dt * 16 + g * 4) = o;
    }
}

extern "C" void kernel_launch(void* const* d_in, const int* in_sizes, int n_in,
                              void* d_out, int out_size, void* d_ws, size_t ws_size,
                              hipStream_t stream) {
    const float* Q = (const float*)d_in[0];
    const float* K = (const float*)d_in[1];
    const float* V = (const float*)d_in[2];
    const float* M = (const float*)d_in[3];
    float* O = (float*)d_out;

    const size_t bytes_kv = 2 * NELEM * 2;                           //  8 MB
    const size_t bytes_ls = (size_t)NSPLIT * NROWS * 4;              //  0.5 MB
    const size_t bytes_pa = (size_t)NSPLIT * NROWS * DMODEL * 4;     // 33.5 MB
    const size_t need_full = bytes_kv + bytes_ls + bytes_pa;         // 42 MB

    unsigned short* Kw  = (unsigned short*)d_ws;
    unsigned short* Vtt = Kw + NELEM;
    float* Plsum = (float*)((char*)d_ws + bytes_kv);
    float* Pacc  = Plsum + NSPLIT * NROWS;

    if (ws_size >= need_full) {
        convert_k<<<1024, 256, 0, stream>>>(K, Kw, (int)(NELEM / 4));
        convert_v<<<1024, 256, 0, stream>>>(V, Vtt);
        attn_staged<NSPLIT><<<512 * NSPLIT, 256, 0, stream>>>(
            Q, Kw, Vtt, M, Pacc, Plsum, O);
        reduce_split<<<(int)(NROWS / 16), 256, 0, stream>>>(Pacc, Plsum, O);
    } else if (ws_size >= bytes_kv) {
        convert_k<<<1024, 256, 0, stream>>>(K, Kw, (int)(NELEM / 4));
        convert_v<<<1024, 256, 0, stream>>>(V, Vtt);
        attn_staged<1><<<512, 256, 0, stream>>>(
            Q, Kw, Vtt, M, nullptr, nullptr, O);
    } else {
        attn_fb<<<512, 256, 0, stream>>>(Q, K, V, M, O);
    }
}

// Round 11
// 110.798 us; speedup vs baseline: 2.7661x; 1.0354x over previous
//
#include <hip/hip_runtime.h>
#include <hip/hip_bf16.h>

#define S_LEN 4096
#define DMODEL 64
#define QBLK 64
#define KBLK 32
#define NKT (S_LEN / KBLK)                  // 128 k-tiles
#define NSPLIT 4
#define NROWS ((size_t)8 * S_LEN)           // 32768 (b,q) rows
#define NELEM ((size_t)8 * S_LEN * DMODEL)  // per-tensor elements (Q/K/V)
#define TSZ 2048                            // elements per 32-key tile
#define QSCALE 0.180336880f                 // 0.125 * log2(e)

typedef __attribute__((ext_vector_type(8))) short bf16x8;
typedef __attribute__((ext_vector_type(4))) float f32x4;
typedef __attribute__((ext_vector_type(4))) unsigned short us4;
typedef __attribute__((ext_vector_type(8))) unsigned short us8;
typedef __attribute__((ext_vector_type(4))) unsigned int u32x4;

__device__ __forceinline__ float bf2f(unsigned short u) {
    unsigned int x = ((unsigned int)u) << 16;
    return __builtin_bit_cast(float, x);
}
__device__ __forceinline__ unsigned short f2bf(float f) {
    unsigned int u = __builtin_bit_cast(unsigned int, f);
    u += 0x7FFFu + ((u >> 16) & 1u);   // RNE
    return (unsigned short)(u >> 16);
}
// pack two floats -> u32 of 2xbf16 via the compiler's packed-cvt path
__device__ __forceinline__ unsigned int packbf2(float lo, float hi) {
    __hip_bfloat162 h = __float22bfloat162_rn(float2{lo, hi});
    unsigned int w;
    __builtin_memcpy(&w, &h, sizeof(w));
    return w;
}
// load 8 fp32, scale, convert to bf16 fragment
__device__ __forceinline__ bf16x8 cvt8s(const float* __restrict__ p, float c) {
    f32x4 a = *(const f32x4*)p;
    f32x4 b = *(const f32x4*)(p + 4);
    bf16x8 r;
    r[0] = (short)f2bf(a[0] * c); r[1] = (short)f2bf(a[1] * c);
    r[2] = (short)f2bf(a[2] * c); r[3] = (short)f2bf(a[3] * c);
    r[4] = (short)f2bf(b[0] * c); r[5] = (short)f2bf(b[1] * c);
    r[6] = (short)f2bf(b[2] * c); r[7] = (short)f2bf(b[3] * c);
    return r;
}

// ---- K: fp32 -> bf16, row-major (each 32-key tile = contiguous 4KB) ----
__global__ __launch_bounds__(256)
void convert_k(const float* __restrict__ src, unsigned short* __restrict__ dst, int n4) {
    int i = blockIdx.x * blockDim.x + threadIdx.x;
    const int stride = gridDim.x * blockDim.x;
    for (; i < n4; i += stride) {
        f32x4 v = ((const f32x4*)src)[i];
        us4 o;
        o[0] = f2bf(v[0]); o[1] = f2bf(v[1]); o[2] = f2bf(v[2]); o[3] = f2bf(v[3]);
        ((us4*)dst)[i] = o;
    }
}

// ---- V: fp32 [b][k][d] -> bf16 tiles Vtt[b][kt][d][pos]; pos e at [d][g*8] holds
//      key 16*(e>>2)+4g+(e&3) == exactly the PV A-fragment ----
__global__ __launch_bounds__(256)
void convert_v(const float* __restrict__ V, unsigned short* __restrict__ Vtt) {
    __shared__ unsigned short lk[KBLK][68];
    const int t  = threadIdx.x;
    const int b  = blockIdx.x >> 7;
    const int kt = blockIdx.x & 127;
    {
        const int key = t >> 3, d0 = (t & 7) * 8;
        const float* src = V + ((size_t)b * S_LEN + kt * KBLK + key) * DMODEL + d0;
        f32x4 a = *(const f32x4*)src;
        f32x4 c = *(const f32x4*)(src + 4);
        lk[key][d0 + 0] = f2bf(a[0]); lk[key][d0 + 1] = f2bf(a[1]);
        lk[key][d0 + 2] = f2bf(a[2]); lk[key][d0 + 3] = f2bf(a[3]);
        lk[key][d0 + 4] = f2bf(c[0]); lk[key][d0 + 5] = f2bf(c[1]);
        lk[key][d0 + 6] = f2bf(c[2]); lk[key][d0 + 7] = f2bf(c[3]);
    }
    __syncthreads();
    {
        const int d = t >> 2, g = t & 3;
        us8 o;
        #pragma unroll
        for (int e = 0; e < 8; ++e) {
            const int key = 16 * (e >> 2) + 4 * g + (e & 3);
            o[e] = lk[key][d];
        }
        *(us8*)(Vtt + ((size_t)b * NKT + kt) * TSZ + d * 32 + g * 8) = o;
    }
}

// ---- mask: fp32 [q][k] -> bf16 tiles Mt[qt][kt][row][pos] (same pos->key map) ----
__global__ __launch_bounds__(256)
void convert_m(const float* __restrict__ M, unsigned short* __restrict__ Mt) {
    const int t   = threadIdx.x;
    const int qt  = blockIdx.x >> 7;
    const int kt  = blockIdx.x & 127;
    const int row = t >> 2, g = t & 3;
    const float* src = M + ((size_t)qt * QBLK + row) * S_LEN + kt * KBLK;
    f32x4 a = *(const f32x4*)(src + 4 * g);
    f32x4 c = *(const f32x4*)(src + 16 + 4 * g);
    us8 o;
    o[0] = f2bf(a[0]); o[1] = f2bf(a[1]); o[2] = f2bf(a[2]); o[3] = f2bf(a[3]);
    o[4] = f2bf(c[0]); o[5] = f2bf(c[1]); o[6] = f2bf(c[2]); o[7] = f2bf(c[3]);
    *(us8*)(Mt + ((size_t)qt * NKT + kt) * TSZ + row * 32 + g * 8) = o;
}

// ---- double-buffered staged attention: ONE barrier per k-step ----
template <bool MT, int SPLITS>
__global__ __launch_bounds__(256)
void attn_dbuf(const float* __restrict__ Q,
               const unsigned short* __restrict__ Kw,
               const unsigned short* __restrict__ Vtt,
               const unsigned short* __restrict__ Mt,
               const float* __restrict__ Mf,
               float* __restrict__ Pacc, float* __restrict__ Plsum,
               float* __restrict__ O) {
    __shared__ __align__(16) unsigned short K_lds[2][KBLK][72];    // 2x4608 B
    __shared__ __align__(16) unsigned short V_lds[2][DMODEL][40];  // 2x5120 B

    const int t    = threadIdx.x;
    const int wave = t >> 6;
    const int lane = t & 63;
    const int g    = lane >> 4;
    const int j    = lane & 15;

    const int bid = blockIdx.x;
    const int b   = bid & 7;             // batch <-> XCD (K/V L2-resident)
    const int qt  = (bid >> 3) & 63;
    const int sp  = (SPLITS > 1) ? (bid >> 9) : 0;
    const int nsteps = NKT / SPLITS;
    const int qrow = qt * QBLK + wave * 16 + j;
    const size_t row = (size_t)b * S_LEN + qrow;

    const float* Qb = Q + (size_t)b * S_LEN * DMODEL;
    const bf16x8 qf0 = cvt8s(Qb + (size_t)qrow * DMODEL + g * 8, QSCALE);
    const bf16x8 qf1 = cvt8s(Qb + (size_t)qrow * DMODEL + g * 8 + 32, QSCALE);

    bf16x8 vones;
    #pragma unroll
    for (int e = 0; e < 8; ++e) vones[e] = (short)0x3F80;

    f32x4 acc[4];
    #pragma unroll
    for (int dt = 0; dt < 4; ++dt) acc[dt] = f32x4{0.f, 0.f, 0.f, 0.f};
    f32x4 accl = {0.f, 0.f, 0.f, 0.f};

    const unsigned short* Kb  = Kw  + (size_t)b * S_LEN * DMODEL;
    const unsigned short* Vb  = Vtt + (size_t)b * NKT * TSZ;
    const unsigned short* Mtl = Mt + (size_t)qt * NKT * TSZ
                                  + (size_t)(wave * 16 + j) * 32 + g * 8;
    const float* mrow = Mf + (size_t)qrow * S_LEN;

    const int kt0 = sp * nsteps;

    // ---- prologue: tile kt0 staged into buf0; tile kt0+1 in regs ----
    us8 kreg = *(const us8*)(Kb + (size_t)kt0 * TSZ + t * 8);
    us8 vreg = *(const us8*)(Vb + (size_t)kt0 * TSZ + t * 8);
    us8 mA{}, mB{};
    f32x4 maA{}, mcA{}, maB{}, mcB{};
    if (MT) mA = *(const us8*)(Mtl + (size_t)kt0 * TSZ);
    else {
        maA = *(const f32x4*)(mrow + kt0 * KBLK + g * 4);
        mcA = *(const f32x4*)(mrow + kt0 * KBLK + 16 + g * 4);
    }
    *(us8*)&K_lds[0][t >> 3][(t & 7) * 8] = kreg;
    *(us8*)&V_lds[0][t >> 2][(t & 3) * 8] = vreg;
    kreg = *(const us8*)(Kb + (size_t)(kt0 + 1) * TSZ + t * 8);
    vreg = *(const us8*)(Vb + (size_t)(kt0 + 1) * TSZ + t * 8);
    if (MT) mB = *(const us8*)(Mtl + (size_t)(kt0 + 1) * TSZ);
    else {
        maB = *(const f32x4*)(mrow + (kt0 + 1) * KBLK + g * 4);
        mcB = *(const f32x4*)(mrow + (kt0 + 1) * KBLK + 16 + g * 4);
    }
    __syncthreads();

    for (int s = 0; s < nsteps; ++s) {
        const int cur = s & 1;

        // 1) stage tile s+1 into the other buffer (regs loaded last iter)
        *(us8*)&K_lds[cur ^ 1][t >> 3][(t & 7) * 8] = kreg;
        *(us8*)&V_lds[cur ^ 1][t >> 2][(t & 3) * 8] = vreg;

        // 2) issue global loads for tile s+2 (clamped) — 2 iters to land
        const int ktn = kt0 + ((s + 2 < nsteps) ? (s + 2) : (nsteps - 1));
        kreg = *(const us8*)(Kb + (size_t)ktn * TSZ + t * 8);
        vreg = *(const us8*)(Vb + (size_t)ktn * TSZ + t * 8);
        us8 mN{};
        f32x4 maN{}, mcN{};
        if (MT) mN = *(const us8*)(Mtl + (size_t)ktn * TSZ);
        else {
            maN = *(const f32x4*)(mrow + ktn * KBLK + g * 4);
            mcN = *(const f32x4*)(mrow + ktn * KBLK + 16 + g * 4);
        }

        // 3) compute step s from buf[cur] + mask regs (tile s)
        bf16x8 kf00 = *(const bf16x8*)&K_lds[cur][j][g * 8];
        bf16x8 kf01 = *(const bf16x8*)&K_lds[cur][j][32 + g * 8];
        bf16x8 kf10 = *(const bf16x8*)&K_lds[cur][16 + j][g * 8];
        bf16x8 kf11 = *(const bf16x8*)&K_lds[cur][16 + j][32 + g * 8];

        f32x4 st0 = {0.f, 0.f, 0.f, 0.f};
        f32x4 st1 = {0.f, 0.f, 0.f, 0.f};
        st0 = __builtin_amdgcn_mfma_f32_16x16x32_bf16(kf00, qf0, st0, 0, 0, 0);
        st0 = __builtin_amdgcn_mfma_f32_16x16x32_bf16(kf01, qf1, st0, 0, 0, 0);
        st1 = __builtin_amdgcn_mfma_f32_16x16x32_bf16(kf10, qf0, st1, 0, 0, 0);
        st1 = __builtin_amdgcn_mfma_f32_16x16x32_bf16(kf11, qf1, st1, 0, 0, 0);
        // st0[r]: key kb+4g+r, st1[r]: key kb+16+4g+r, column q = qrow

        float m0[4], m1[4];
        #pragma unroll
        for (int r = 0; r < 4; ++r) {
            if (MT) { m0[r] = bf2f(mA[r]); m1[r] = bf2f(mA[4 + r]); }
            else    { m0[r] = maA[r];       m1[r] = mcA[r]; }
        }

        float e0[4], e1[4];
        #pragma unroll
        for (int r = 0; r < 4; ++r) {
            e0[r] = __builtin_amdgcn_exp2f(st0[r]) * m0[r];
            e1[r] = __builtin_amdgcn_exp2f(st1[r]) * m1[r];
        }
        u32x4 pw;
        pw[0] = packbf2(e0[0], e0[1]);
        pw[1] = packbf2(e0[2], e0[3]);
        pw[2] = packbf2(e1[0], e1[1]);
        pw[3] = packbf2(e1[2], e1[3]);
        const bf16x8 pf = __builtin_bit_cast(bf16x8, pw);  // slot e: key kb+16*(e>>2)+4g+(e&3)

        accl = __builtin_amdgcn_mfma_f32_16x16x32_bf16(vones, pf, accl, 0, 0, 0);
        #pragma unroll
        for (int dt = 0; dt < 4; ++dt) {
            bf16x8 vf = *(const bf16x8*)&V_lds[cur][dt * 16 + j][g * 8];
            acc[dt] = __builtin_amdgcn_mfma_f32_16x16x32_bf16(vf, pf, acc[dt], 0, 0, 0);
        }

        // 4) shift mask pipeline
        mA = mB; mB = mN;
        maA = maB; mcA = mcB; maB = maN; mcB = mcN;

        // 5) single barrier: buf[cur^1] writes visible; buf[cur] reads done
        __syncthreads();
    }

    const float lsum = accl[0];   // ones^T*P: full split-sum in every reg

    if (SPLITS > 1) {
        if (g == 0) Plsum[(size_t)sp * NROWS + row] = lsum;
        float* pr = Pacc + ((size_t)sp * NROWS + row) * DMODEL;
        #pragma unroll
        for (int dt = 0; dt < 4; ++dt)
            *(f32x4*)(pr + dt * 16 + g * 4) = acc[dt];
    } else {
        const float inv = 1.0f / lsum;
        float* orow = O + row * DMODEL;
        #pragma unroll
        for (int dt = 0; dt < 4; ++dt) {
            f32x4 o;
            #pragma unroll
            for (int r = 0; r < 4; ++r) o[r] = acc[dt][r] * inv;
            *(f32x4*)(orow + dt * 16 + g * 4) = o;
        }
    }
}

// ---- reduce: O = sum_s acc_s / sum_s lsum_s ----
__global__ __launch_bounds__(256)
void reduce_split(const float* __restrict__ Pacc, const float* __restrict__ Plsum,
                  float* __restrict__ O) {
    const int t = threadIdx.x;
    const size_t rid = (size_t)blockIdx.x * 16 + (t >> 4);
    const int seg = (t & 15) * 4;

    float ls = 0.f;
    f32x4 a = {0.f, 0.f, 0.f, 0.f};
    #pragma unroll
    for (int s = 0; s < NSPLIT; ++s) {
        ls += Plsum[(size_t)s * NROWS + rid];
        f32x4 v = *(const f32x4*)(Pacc + ((size_t)s * NROWS + rid) * DMODEL + seg);
        a[0] += v[0]; a[1] += v[1]; a[2] += v[2]; a[3] += v[3];
    }
    const float inv = 1.0f / ls;
    f32x4 o = {a[0] * inv, a[1] * inv, a[2] * inv, a[3] * inv};
    *(f32x4*)(O + rid * DMODEL + seg) = o;
}

// ---- no-workspace fallback ----
__global__ __launch_bounds__(256)
void attn_fb(const float* __restrict__ Q, const float* __restrict__ Kf,
             const float* __restrict__ Vf, const float* __restrict__ M,
             float* __restrict__ O) {
    const int t    = threadIdx.x;
    const int wave = t >> 6;
    const int lane = t & 63;
    const int g    = lane >> 4;
    const int j    = lane & 15;
    const int bid  = blockIdx.x;
    const int b    = bid & 7;
    const int qt   = bid >> 3;
    const int qrow = qt * QBLK + wave * 16 + j;

    const float* Qb = Q + (size_t)b * S_LEN * DMODEL;
    const bf16x8 qf0 = cvt8s(Qb + (size_t)qrow * DMODEL + g * 8, QSCALE);
    const bf16x8 qf1 = cvt8s(Qb + (size_t)qrow * DMODEL + g * 8 + 32, QSCALE);

    f32x4 acc[4];
    #pragma unroll
    for (int dt = 0; dt < 4; ++dt) acc[dt] = f32x4{0.f, 0.f, 0.f, 0.f};
    float lsum = 0.f;

    const float* Kfb = Kf + (size_t)b * S_LEN * DMODEL;
    const float* Vfb = Vf + (size_t)b * S_LEN * DMODEL;
    const float* mrow = M + (size_t)qrow * S_LEN;

    int kg[8];
    #pragma unroll
    for (int e = 0; e < 8; ++e) kg[e] = 16 * (e >> 2) + 4 * g + (e & 3);

    for (int kt = 0; kt < NKT; ++kt) {
        const int kb = kt * KBLK;
        bf16x8 kf00 = cvt8s(Kfb + (size_t)(kb + j) * DMODEL + g * 8, 1.0f);
        bf16x8 kf01 = cvt8s(Kfb + (size_t)(kb + j) * DMODEL + g * 8 + 32, 1.0f);
        bf16x8 kf10 = cvt8s(Kfb + (size_t)(kb + 16 + j) * DMODEL + g * 8, 1.0f);
        bf16x8 kf11 = cvt8s(Kfb + (size_t)(kb + 16 + j) * DMODEL + g * 8 + 32, 1.0f);

        f32x4 st0 = {0.f, 0.f, 0.f, 0.f};
        f32x4 st1 = {0.f, 0.f, 0.f, 0.f};
        st0 = __builtin_amdgcn_mfma_f32_16x16x32_bf16(kf00, qf0, st0, 0, 0, 0);
        st0 = __builtin_amdgcn_mfma_f32_16x16x32_bf16(kf01, qf1, st0, 0, 0, 0);
        st1 = __builtin_amdgcn_mfma_f32_16x16x32_bf16(kf10, qf0, st1, 0, 0, 0);
        st1 = __builtin_amdgcn_mfma_f32_16x16x32_bf16(kf11, qf1, st1, 0, 0, 0);

        f32x4 m0 = *(const f32x4*)(mrow + kb + g * 4);
        f32x4 m1 = *(const f32x4*)(mrow + kb + 16 + g * 4);

        bf16x8 pf;
        #pragma unroll
        for (int r = 0; r < 4; ++r) {
            float w0 = __builtin_amdgcn_exp2f(st0[r]) * m0[r];
            float w1 = __builtin_amdgcn_exp2f(st1[r]) * m1[r];
            lsum += w0 + w1;
            pf[r]     = (short)f2bf(w0);
            pf[4 + r] = (short)f2bf(w1);
        }

        #pragma unroll
        for (int dt = 0; dt < 4; ++dt) {
            bf16x8 vf;
            #pragma unroll
            for (int e = 0; e < 8; ++e)
                vf[e] = (short)f2bf(Vfb[(size_t)(kb + kg[e]) * DMODEL + dt * 16 + j]);
            acc[dt] = __builtin_amdgcn_mfma_f32_16x16x32_bf16(vf, pf, acc[dt], 0, 0, 0);
        }
    }

    lsum += __shfl_xor(lsum, 16, 64);
    lsum += __shfl_xor(lsum, 32, 64);
    const float inv = 1.0f / lsum;

    float* orow = O + ((size_t)b * S_LEN + qrow) * DMODEL;
    #pragma unroll
    for (int dt = 0; dt < 4; ++dt) {
        f32x4 o;
        #pragma unroll
        for (int r = 0; r < 4; ++r) o[r] = acc[dt][r] * inv;
        *(f32x4*)(orow + dt * 16 + g * 4) = o;
    }
}

extern "C" void kernel_launch(void* const* d_in, const int* in_sizes, int n_in,
                              void* d_out, int out_size, void* d_ws, size_t ws_size,
                              hipStream_t stream) {
    const float* Q = (const float*)d_in[0];
    const float* K = (const float*)d_in[1];
    const float* V = (const float*)d_in[2];
    const float* M = (const float*)d_in[3];
    float* O = (float*)d_out;

    const size_t bytes_kv = 2 * NELEM * 2;                           //  8 MB
    const size_t bytes_m  = (size_t)S_LEN * S_LEN * 2;               // 32 MB
    const size_t bytes_ls = (size_t)NSPLIT * NROWS * 4;              //  0.5 MB
    const size_t bytes_pa = (size_t)NSPLIT * NROWS * DMODEL * 4;     // 33.5 MB

    const size_t need_full = bytes_kv + bytes_m + bytes_ls + bytes_pa;  // 74 MB
    const size_t need_mid  = bytes_kv + bytes_ls + bytes_pa;            // 42 MB

    unsigned short* Kw  = (unsigned short*)d_ws;
    unsigned short* Vtt = Kw + NELEM;

    if (ws_size >= need_full) {
        unsigned short* Mt = Vtt + NELEM;
        float* Plsum = (float*)((char*)d_ws + bytes_kv + bytes_m);
        float* Pacc  = Plsum + NSPLIT * NROWS;
        convert_k<<<1024, 256, 0, stream>>>(K, Kw, (int)(NELEM / 4));
        convert_v<<<1024, 256, 0, stream>>>(V, Vtt);
        convert_m<<<64 * 128, 256, 0, stream>>>(M, Mt);
        attn_dbuf<true, NSPLIT><<<512 * NSPLIT, 256, 0, stream>>>(
            Q, Kw, Vtt, Mt, M, Pacc, Plsum, O);
        reduce_split<<<(int)(NROWS / 16), 256, 0, stream>>>(Pacc, Plsum, O);
    } else if (ws_size >= need_mid) {
        float* Plsum = (float*)((char*)d_ws + bytes_kv);
        float* Pacc  = Plsum + NSPLIT * NROWS;
        convert_k<<<1024, 256, 0, stream>>>(K, Kw, (int)(NELEM / 4));
        convert_v<<<1024, 256, 0, stream>>>(V, Vtt);
        attn_dbuf<false, NSPLIT><<<512 * NSPLIT, 256, 0, stream>>>(
            Q, Kw, Vtt, nullptr, M, Pacc, Plsum, O);
        reduce_split<<<(int)(NROWS / 16), 256, 0, stream>>>(Pacc, Plsum, O);
    } else if (ws_size >= bytes_kv) {
        convert_k<<<1024, 256, 0, stream>>>(K, Kw, (int)(NELEM / 4));
        convert_v<<<1024, 256, 0, stream>>>(V, Vtt);
        attn_dbuf<false, 1><<<512, 256, 0, stream>>>(
            Q, Kw, Vtt, nullptr, M, nullptr, nullptr, O);
    } else {
        attn_fb<<<512, 256, 0, stream>>>(Q, K, V, M, O);
    }
}

// Round 12
// 108.553 us; speedup vs baseline: 2.8233x; 1.0207x over previous
//
#include <hip/hip_runtime.h>

#define S_LEN 4096
#define DMODEL 64
#define QBLK 64
#define KBLK 32
#define NKT (S_LEN / KBLK)                  // 128 k-tiles
#define NSPLIT 4
#define NROWS ((size_t)8 * S_LEN)           // 32768 (b,q) rows
#define NELEM ((size_t)8 * S_LEN * DMODEL)  // per-tensor elements (Q/K/V)
#define TSZ 2048                            // elements per 32-key tile (4KB bf16)
#define QSCALE 0.180336880f                 // 0.125 * log2(e)

typedef __attribute__((ext_vector_type(8))) short bf16x8;
typedef __attribute__((ext_vector_type(4))) float f32x4;
typedef __attribute__((ext_vector_type(4))) unsigned short us4;
typedef __attribute__((ext_vector_type(8))) unsigned short us8;
typedef __attribute__((ext_vector_type(4))) unsigned int u32x4;

__device__ __forceinline__ float bf2f(unsigned short u) {
    unsigned int x = ((unsigned int)u) << 16;
    return __builtin_bit_cast(float, x);
}
__device__ __forceinline__ unsigned short f2bf(float f) {
    unsigned int u = __builtin_bit_cast(unsigned int, f);
    u += 0x7FFFu + ((u >> 16) & 1u);   // RNE
    return (unsigned short)(u >> 16);
}
__device__ __forceinline__ unsigned int packbf2(float lo, float hi) {
    return (unsigned int)f2bf(lo) | ((unsigned int)f2bf(hi) << 16);
}
__device__ __forceinline__ bf16x8 cvt8s(const float* __restrict__ p, float c) {
    f32x4 a = *(const f32x4*)p;
    f32x4 b = *(const f32x4*)(p + 4);
    bf16x8 r;
    r[0] = (short)f2bf(a[0] * c); r[1] = (short)f2bf(a[1] * c);
    r[2] = (short)f2bf(a[2] * c); r[3] = (short)f2bf(a[3] * c);
    r[4] = (short)f2bf(b[0] * c); r[5] = (short)f2bf(b[1] * c);
    r[6] = (short)f2bf(b[2] * c); r[7] = (short)f2bf(b[3] * c);
    return r;
}

// ---- K: fp32 [b][k][d] -> fragment-major tiles Ktt[b][kt][frag][lane] (us8 each) ----
// frag 0: K[kb+j][g*8..+7], 1: K[kb+j][32+g*8..], 2: K[kb+16+j][g*8..], 3: +32, l=(g<<4)|j
__global__ __launch_bounds__(256)
void convert_k_frag(const float* __restrict__ K, unsigned short* __restrict__ Ktt) {
    const int t  = threadIdx.x;
    const int b  = blockIdx.x >> 7;
    const int kt = blockIdx.x & 127;
    const int l = t & 63, frag = t >> 6;
    const int j = l & 15, g = l >> 4;
    const int row = kt * KBLK + ((frag >> 1) & 1) * 16 + j;
    const int col = (frag & 1) * 32 + g * 8;
    const float* src = K + ((size_t)b * S_LEN + row) * DMODEL + col;
    f32x4 a = *(const f32x4*)src;
    f32x4 c = *(const f32x4*)(src + 4);
    us8 o;
    o[0] = f2bf(a[0]); o[1] = f2bf(a[1]); o[2] = f2bf(a[2]); o[3] = f2bf(a[3]);
    o[4] = f2bf(c[0]); o[5] = f2bf(c[1]); o[6] = f2bf(c[2]); o[7] = f2bf(c[3]);
    *(us8*)(Ktt + ((size_t)(b * NKT + kt)) * TSZ + t * 8) = o;
}

// ---- V: fp32 [b][k][d] -> fragment-major tiles Vtt[b][kt][dt][lane]; lane l=(g,j),
//      slot e = V[kb + 16*(e>>2)+4g+(e&3)][dt*16+j] == the PV A-fragment ----
__global__ __launch_bounds__(256)
void convert_v_frag(const float* __restrict__ V, unsigned short* __restrict__ Vtt) {
    __shared__ unsigned short lk[KBLK][68];
    const int t  = threadIdx.x;
    const int b  = blockIdx.x >> 7;
    const int kt = blockIdx.x & 127;
    {
        const int key = t >> 3, d0 = (t & 7) * 8;
        const float* src = V + ((size_t)b * S_LEN + kt * KBLK + key) * DMODEL + d0;
        f32x4 a = *(const f32x4*)src;
        f32x4 c = *(const f32x4*)(src + 4);
        lk[key][d0 + 0] = f2bf(a[0]); lk[key][d0 + 1] = f2bf(a[1]);
        lk[key][d0 + 2] = f2bf(a[2]); lk[key][d0 + 3] = f2bf(a[3]);
        lk[key][d0 + 4] = f2bf(c[0]); lk[key][d0 + 5] = f2bf(c[1]);
        lk[key][d0 + 6] = f2bf(c[2]); lk[key][d0 + 7] = f2bf(c[3]);
    }
    __syncthreads();
    {
        const int l = t & 63, dt = t >> 6;
        const int j = l & 15, g = l >> 4;
        us8 o;
        #pragma unroll
        for (int e = 0; e < 8; ++e) {
            const int key = 16 * (e >> 2) + 4 * g + (e & 3);
            o[e] = lk[key][dt * 16 + j];
        }
        *(us8*)(Vtt + ((size_t)(b * NKT + kt)) * TSZ + t * 8) = o;
    }
}

// ---- mask: fp32 [q][k] -> per-wave-linear bf16 tiles Mt[qt][kt][t]; thread t=(w,l):
//      row = w*16+(l&15), g=l>>4, slot e -> key kt*32 + 16*(e>>2)+4g+(e&3) ----
__global__ __launch_bounds__(256)
void convert_m_frag(const float* __restrict__ M, unsigned short* __restrict__ Mt) {
    const int t  = threadIdx.x;
    const int qt = blockIdx.x >> 7;
    const int kt = blockIdx.x & 127;
    const int l = t & 63, w = t >> 6;
    const int row = w * 16 + (l & 15), g = l >> 4;
    const float* src = M + ((size_t)(qt * QBLK + row)) * S_LEN + kt * KBLK;
    f32x4 a = *(const f32x4*)(src + 4 * g);
    f32x4 c = *(const f32x4*)(src + 16 + 4 * g);
    us8 o;
    o[0] = f2bf(a[0]); o[1] = f2bf(a[1]); o[2] = f2bf(a[2]); o[3] = f2bf(a[3]);
    o[4] = f2bf(c[0]); o[5] = f2bf(c[1]); o[6] = f2bf(c[2]); o[7] = f2bf(c[3]);
    *(us8*)(Mt + ((size_t)(qt * NKT + kt)) * TSZ + t * 8) = o;
}

// ---- attention: fragment-major LDS dbuf, linear ds r/w, unroll-2, split-K ----
template <int SPLITS>
__global__ __launch_bounds__(256)
void attn_frag(const float* __restrict__ Q,
               const unsigned short* __restrict__ Ktt,
               const unsigned short* __restrict__ Vtt,
               const unsigned short* __restrict__ Mt,
               float* __restrict__ Pacc, float* __restrict__ Plsum,
               float* __restrict__ O) {
    // S: K buf0 [0,2048), K buf1 [2048,4096), V buf0 [4096,6144), V buf1 [6144,8192) (ushort idx)
    __shared__ __align__(16) unsigned short S[8192];   // 16 KB

    const int t    = threadIdx.x;
    const int wave = t >> 6;
    const int l    = t & 63;
    const int g    = l >> 4;
    const int j    = l & 15;

    const int bid = blockIdx.x;
    const int b   = bid & 7;             // batch <-> XCD (K/V L2-resident)
    const int qt  = (bid >> 3) & 63;
    const int sp  = (SPLITS > 1) ? (bid >> 9) : 0;
    const int nsteps = NKT / SPLITS;
    const int qrow = qt * QBLK + wave * 16 + j;
    const size_t row = (size_t)b * S_LEN + qrow;

    const float* Qb = Q + (size_t)b * S_LEN * DMODEL;
    const bf16x8 qf0 = cvt8s(Qb + (size_t)qrow * DMODEL + g * 8, QSCALE);
    const bf16x8 qf1 = cvt8s(Qb + (size_t)qrow * DMODEL + g * 8 + 32, QSCALE);

    bf16x8 vones;
    #pragma unroll
    for (int e = 0; e < 8; ++e) vones[e] = (short)0x3F80;

    f32x4 acc[4];
    #pragma unroll
    for (int dt = 0; dt < 4; ++dt) acc[dt] = f32x4{0.f, 0.f, 0.f, 0.f};
    f32x4 accl = {0.f, 0.f, 0.f, 0.f};

    const int kt0 = sp * nsteps;
    const unsigned short* pk = Ktt + (size_t)(b * NKT + kt0) * TSZ + t * 8;
    const unsigned short* pv = Vtt + (size_t)(b * NKT + kt0) * TSZ + t * 8;
    const unsigned short* pm = Mt  + (size_t)(qt * NKT + kt0) * TSZ + t * 8;

    // ---- prologue: tile kt0 -> buf0; tile kt0+1 -> regs; masks kt0/kt0+1 -> mA/mB ----
    us8 kreg = *(const us8*)pk;
    us8 vreg = *(const us8*)pv;
    us8 mA   = *(const us8*)pm;
    *(us8*)&S[t * 8]        = kreg;
    *(us8*)&S[4096 + t * 8] = vreg;
    kreg = *(const us8*)(pk + TSZ);
    vreg = *(const us8*)(pv + TSZ);
    us8 mB = *(const us8*)(pm + TSZ);
    pk += 2 * TSZ; pv += 2 * TSZ; pm += 2 * TSZ;   // now point at tile s+2
    __syncthreads();

    // NOTE: prefetch pointers run 1-2 tiles past the split range on the last steps;
    // those reads land in the adjacent ws arrays (in-bounds) and are never consumed.
    for (int p = 0; p < nsteps / 2; ++p) {
        #pragma unroll
        for (int u = 0; u < 2; ++u) {
            // 1) stage tile s+1 (in regs) into buf u^1 — linear t*16, conflict-free
            *(us8*)&S[(u ^ 1) * 2048 + t * 8]        = kreg;
            *(us8*)&S[4096 + (u ^ 1) * 2048 + t * 8] = vreg;

            // 2) issue loads for tile s+2 (land during next step's compute)
            kreg = *(const us8*)pk; pk += TSZ;
            vreg = *(const us8*)pv; pv += TSZ;

            // 3) compute step s from buf u (all offsets compile-time via unroll)
            bf16x8 kf0 = *(const bf16x8*)&S[u * 2048 + 0 * 512 + l * 8];
            bf16x8 kf1 = *(const bf16x8*)&S[u * 2048 + 1 * 512 + l * 8];
            bf16x8 kf2 = *(const bf16x8*)&S[u * 2048 + 2 * 512 + l * 8];
            bf16x8 kf3 = *(const bf16x8*)&S[u * 2048 + 3 * 512 + l * 8];

            f32x4 st0 = {0.f, 0.f, 0.f, 0.f};
            f32x4 st1 = {0.f, 0.f, 0.f, 0.f};
            st0 = __builtin_amdgcn_mfma_f32_16x16x32_bf16(kf0, qf0, st0, 0, 0, 0);
            st0 = __builtin_amdgcn_mfma_f32_16x16x32_bf16(kf1, qf1, st0, 0, 0, 0);
            st1 = __builtin_amdgcn_mfma_f32_16x16x32_bf16(kf2, qf0, st1, 0, 0, 0);
            st1 = __builtin_amdgcn_mfma_f32_16x16x32_bf16(kf3, qf1, st1, 0, 0, 0);
            // st0[r]: key kb+4g+r, st1[r]: key kb+16+4g+r, column q = qrow

            const us8 mcur = u ? mB : mA;
            float e0[4], e1[4];
            #pragma unroll
            for (int r = 0; r < 4; ++r) {
                e0[r] = __builtin_amdgcn_exp2f(st0[r]) * bf2f(mcur[r]);
                e1[r] = __builtin_amdgcn_exp2f(st1[r]) * bf2f(mcur[4 + r]);
            }
            u32x4 pw;
            pw[0] = packbf2(e0[0], e0[1]);
            pw[1] = packbf2(e0[2], e0[3]);
            pw[2] = packbf2(e1[0], e1[1]);
            pw[3] = packbf2(e1[2], e1[3]);
            const bf16x8 pf = __builtin_bit_cast(bf16x8, pw);  // slot e: key kb+16*(e>>2)+4g+(e&3)

            // 4) reload mask for step s+2 into the same (static) slot
            if (u == 0) { mA = *(const us8*)pm; } else { mB = *(const us8*)pm; }
            pm += TSZ;

            accl = __builtin_amdgcn_mfma_f32_16x16x32_bf16(vones, pf, accl, 0, 0, 0);
            #pragma unroll
            for (int dt = 0; dt < 4; ++dt) {
                bf16x8 vf = *(const bf16x8*)&S[4096 + u * 2048 + dt * 512 + l * 8];
                acc[dt] = __builtin_amdgcn_mfma_f32_16x16x32_bf16(vf, pf, acc[dt], 0, 0, 0);
            }

            // 5) one barrier: buf u^1 writes visible; all reads of buf u done
            __syncthreads();
        }
    }

    const float lsum = accl[0];   // ones^T*P: full split-sum in every reg

    if (SPLITS > 1) {
        if (g == 0) Plsum[(size_t)sp * NROWS + row] = lsum;
        float* pr = Pacc + ((size_t)sp * NROWS + row) * DMODEL;
        #pragma unroll
        for (int dt = 0; dt < 4; ++dt)
            *(f32x4*)(pr + dt * 16 + g * 4) = acc[dt];
    } else {
        const float inv = 1.0f / lsum;
        float* orow = O + row * DMODEL;
        #pragma unroll
        for (int dt = 0; dt < 4; ++dt) {
            f32x4 o;
            #pragma unroll
            for (int r = 0; r < 4; ++r) o[r] = acc[dt][r] * inv;
            *(f32x4*)(orow + dt * 16 + g * 4) = o;
        }
    }
}

// ---- reduce: O = sum_s acc_s / sum_s lsum_s ----
__global__ __launch_bounds__(256)
void reduce_split(const float* __restrict__ Pacc, const float* __restrict__ Plsum,
                  float* __restrict__ O) {
    const int t = threadIdx.x;
    const size_t rid = (size_t)blockIdx.x * 16 + (t >> 4);
    const int seg = (t & 15) * 4;

    float ls = 0.f;
    f32x4 a = {0.f, 0.f, 0.f, 0.f};
    #pragma unroll
    for (int s = 0; s < NSPLIT; ++s) {
        ls += Plsum[(size_t)s * NROWS + rid];
        f32x4 v = *(const f32x4*)(Pacc + ((size_t)s * NROWS + rid) * DMODEL + seg);
        a[0] += v[0]; a[1] += v[1]; a[2] += v[2]; a[3] += v[3];
    }
    const float inv = 1.0f / ls;
    f32x4 o = {a[0] * inv, a[1] * inv, a[2] * inv, a[3] * inv};
    *(f32x4*)(O + rid * DMODEL + seg) = o;
}

// ---- no-workspace fallback: direct fp32 loads (validated math) ----
__global__ __launch_bounds__(256)
void attn_fb(const float* __restrict__ Q, const float* __restrict__ Kf,
             const float* __restrict__ Vf, const float* __restrict__ M,
             float* __restrict__ O) {
    const int t    = threadIdx.x;
    const int wave = t >> 6;
    const int lane = t & 63;
    const int g    = lane >> 4;
    const int j    = lane & 15;
    const int bid  = blockIdx.x;
    const int b    = bid & 7;
    const int qt   = bid >> 3;
    const int qrow = qt * QBLK + wave * 16 + j;

    const float* Qb = Q + (size_t)b * S_LEN * DMODEL;
    const bf16x8 qf0 = cvt8s(Qb + (size_t)qrow * DMODEL + g * 8, QSCALE);
    const bf16x8 qf1 = cvt8s(Qb + (size_t)qrow * DMODEL + g * 8 + 32, QSCALE);

    f32x4 acc[4];
    #pragma unroll
    for (int dt = 0; dt < 4; ++dt) acc[dt] = f32x4{0.f, 0.f, 0.f, 0.f};
    float lsum = 0.f;

    const float* Kfb = Kf + (size_t)b * S_LEN * DMODEL;
    const float* Vfb = Vf + (size_t)b * S_LEN * DMODEL;
    const float* mrow = M + (size_t)qrow * S_LEN;

    int kg[8];
    #pragma unroll
    for (int e = 0; e < 8; ++e) kg[e] = 16 * (e >> 2) + 4 * g + (e & 3);

    for (int kt = 0; kt < NKT; ++kt) {
        const int kb = kt * KBLK;
        bf16x8 kf00 = cvt8s(Kfb + (size_t)(kb + j) * DMODEL + g * 8, 1.0f);
        bf16x8 kf01 = cvt8s(Kfb + (size_t)(kb + j) * DMODEL + g * 8 + 32, 1.0f);
        bf16x8 kf10 = cvt8s(Kfb + (size_t)(kb + 16 + j) * DMODEL + g * 8, 1.0f);
        bf16x8 kf11 = cvt8s(Kfb + (size_t)(kb + 16 + j) * DMODEL + g * 8 + 32, 1.0f);

        f32x4 st0 = {0.f, 0.f, 0.f, 0.f};
        f32x4 st1 = {0.f, 0.f, 0.f, 0.f};
        st0 = __builtin_amdgcn_mfma_f32_16x16x32_bf16(kf00, qf0, st0, 0, 0, 0);
        st0 = __builtin_amdgcn_mfma_f32_16x16x32_bf16(kf01, qf1, st0, 0, 0, 0);
        st1 = __builtin_amdgcn_mfma_f32_16x16x32_bf16(kf10, qf0, st1, 0, 0, 0);
        st1 = __builtin_amdgcn_mfma_f32_16x16x32_bf16(kf11, qf1, st1, 0, 0, 0);

        f32x4 m0 = *(const f32x4*)(mrow + kb + g * 4);
        f32x4 m1 = *(const f32x4*)(mrow + kb + 16 + g * 4);

        bf16x8 pf;
        #pragma unroll
        for (int r = 0; r < 4; ++r) {
            float w0 = __builtin_amdgcn_exp2f(st0[r]) * m0[r];
            float w1 = __builtin_amdgcn_exp2f(st1[r]) * m1[r];
            lsum += w0 + w1;
            pf[r]     = (short)f2bf(w0);
            pf[4 + r] = (short)f2bf(w1);
        }

        #pragma unroll
        for (int dt = 0; dt < 4; ++dt) {
            bf16x8 vf;
            #pragma unroll
            for (int e = 0; e < 8; ++e)
                vf[e] = (short)f2bf(Vfb[(size_t)(kb + kg[e]) * DMODEL + dt * 16 + j]);
            acc[dt] = __builtin_amdgcn_mfma_f32_16x16x32_bf16(vf, pf, acc[dt], 0, 0, 0);
        }
    }

    lsum += __shfl_xor(lsum, 16, 64);
    lsum += __shfl_xor(lsum, 32, 64);
    const float inv = 1.0f / lsum;

    float* orow = O + ((size_t)b * S_LEN + qrow) * DMODEL;
    #pragma unroll
    for (int dt = 0; dt < 4; ++dt) {
        f32x4 o;
        #pragma unroll
        for (int r = 0; r < 4; ++r) o[r] = acc[dt][r] * inv;
        *(f32x4*)(orow + dt * 16 + g * 4) = o;
    }
}

extern "C" void kernel_launch(void* const* d_in, const int* in_sizes, int n_in,
                              void* d_out, int out_size, void* d_ws, size_t ws_size,
                              hipStream_t stream) {
    const float* Q = (const float*)d_in[0];
    const float* K = (const float*)d_in[1];
    const float* V = (const float*)d_in[2];
    const float* M = (const float*)d_in[3];
    float* O = (float*)d_out;

    const size_t bytes_kv = 2 * NELEM * 2;                           //  8 MB
    const size_t bytes_m  = (size_t)S_LEN * S_LEN * 2;               // 32 MB
    const size_t bytes_ls = (size_t)NSPLIT * NROWS * 4;              //  0.5 MB
    const size_t bytes_pa = (size_t)NSPLIT * NROWS * DMODEL * 4;     // 33.5 MB
    const size_t need_full = bytes_kv + bytes_m + bytes_ls + bytes_pa;  // 74 MB

    if (ws_size >= need_full) {
        unsigned short* Ktt = (unsigned short*)d_ws;
        unsigned short* Vtt = Ktt + NELEM;
        unsigned short* Mt  = Vtt + NELEM;
        float* Plsum = (float*)((char*)d_ws + bytes_kv + bytes_m);
        float* Pacc  = Plsum + NSPLIT * NROWS;
        convert_k_frag<<<8 * 128, 256, 0, stream>>>(K, Ktt);
        convert_v_frag<<<8 * 128, 256, 0, stream>>>(V, Vtt);
        convert_m_frag<<<64 * 128, 256, 0, stream>>>(M, Mt);
        attn_frag<NSPLIT><<<512 * NSPLIT, 256, 0, stream>>>(
            Q, Ktt, Vtt, Mt, Pacc, Plsum, O);
        reduce_split<<<(int)(NROWS / 16), 256, 0, stream>>>(Pacc, Plsum, O);
    } else {
        attn_fb<<<512, 256, 0, stream>>>(Q, K, V, M, O);
    }
}

// Round 13
// 103.680 us; speedup vs baseline: 2.9560x; 1.0470x over previous
//
#include <hip/hip_runtime.h>

#define S_LEN 4096
#define DMODEL 64
#define QBLK 64
#define KBLK 32
#define NKT (S_LEN / KBLK)                  // 128 k-tiles
#define NSPLIT 4
#define NROWS ((size_t)8 * S_LEN)           // 32768 (b,q) rows
#define NELEM ((size_t)8 * S_LEN * DMODEL)  // per-tensor elements (Q/K/V)
#define TSZ 2048                            // elements per 32-key tile (4KB bf16)
#define QSCALE 0.180336880f                 // 0.125 * log2(e)

typedef __attribute__((ext_vector_type(8))) short bf16x8;
typedef __attribute__((ext_vector_type(4))) float f32x4;
typedef __attribute__((ext_vector_type(4))) unsigned short us4;
typedef __attribute__((ext_vector_type(8))) unsigned short us8;
typedef __attribute__((ext_vector_type(4))) unsigned int u32x4;

// barrier WITHOUT the vmcnt(0) drain __syncthreads would emit:
// LDS visibility needs only lgkmcnt(0); in-flight global prefetches may span.
#define LDS_BARRIER()                                            \
    do {                                                         \
        asm volatile("s_waitcnt lgkmcnt(0)" ::: "memory");       \
        __builtin_amdgcn_s_barrier();                            \
    } while (0)

__device__ __forceinline__ float bf2f(unsigned short u) {
    unsigned int x = ((unsigned int)u) << 16;
    return __builtin_bit_cast(float, x);
}
__device__ __forceinline__ unsigned short f2bf(float f) {
    unsigned int u = __builtin_bit_cast(unsigned int, f);
    u += 0x7FFFu + ((u >> 16) & 1u);   // RNE
    return (unsigned short)(u >> 16);
}
__device__ __forceinline__ unsigned int packbf2(float lo, float hi) {
    return (unsigned int)f2bf(lo) | ((unsigned int)f2bf(hi) << 16);
}
__device__ __forceinline__ bf16x8 cvt8s(const float* __restrict__ p, float c) {
    f32x4 a = *(const f32x4*)p;
    f32x4 b = *(const f32x4*)(p + 4);
    bf16x8 r;
    r[0] = (short)f2bf(a[0] * c); r[1] = (short)f2bf(a[1] * c);
    r[2] = (short)f2bf(a[2] * c); r[3] = (short)f2bf(a[3] * c);
    r[4] = (short)f2bf(b[0] * c); r[5] = (short)f2bf(b[1] * c);
    r[6] = (short)f2bf(b[2] * c); r[7] = (short)f2bf(b[3] * c);
    return r;
}

// ---- fused converts: one launch. blocks [0,1024): K, [1024,2048): V, [2048,10240): M ----
__global__ __launch_bounds__(256)
void convert_all(const float* __restrict__ K, const float* __restrict__ V,
                 const float* __restrict__ M,
                 unsigned short* __restrict__ Ktt, unsigned short* __restrict__ Vtt,
                 unsigned short* __restrict__ Mt) {
    const int t = threadIdx.x;
    int bid = blockIdx.x;

    if (bid < 1024) {
        // K: fp32 [b][k][d] -> fragment-major Ktt[b][kt][frag][lane]
        const int b  = bid >> 7;
        const int kt = bid & 127;
        const int l = t & 63, frag = t >> 6;
        const int j = l & 15, g = l >> 4;
        const int row = kt * KBLK + ((frag >> 1) & 1) * 16 + j;
        const int col = (frag & 1) * 32 + g * 8;
        const float* src = K + ((size_t)b * S_LEN + row) * DMODEL + col;
        f32x4 a = *(const f32x4*)src;
        f32x4 c = *(const f32x4*)(src + 4);
        us8 o;
        o[0] = f2bf(a[0]); o[1] = f2bf(a[1]); o[2] = f2bf(a[2]); o[3] = f2bf(a[3]);
        o[4] = f2bf(c[0]); o[5] = f2bf(c[1]); o[6] = f2bf(c[2]); o[7] = f2bf(c[3]);
        *(us8*)(Ktt + ((size_t)(b * NKT + kt)) * TSZ + t * 8) = o;
    } else if (bid < 2048) {
        // V: fp32 [b][k][d] -> fragment-major Vtt[b][kt][dt][lane] (transpose via LDS)
        bid -= 1024;
        __shared__ unsigned short lk[KBLK][68];
        const int b  = bid >> 7;
        const int kt = bid & 127;
        {
            const int key = t >> 3, d0 = (t & 7) * 8;
            const float* src = V + ((size_t)b * S_LEN + kt * KBLK + key) * DMODEL + d0;
            f32x4 a = *(const f32x4*)src;
            f32x4 c = *(const f32x4*)(src + 4);
            lk[key][d0 + 0] = f2bf(a[0]); lk[key][d0 + 1] = f2bf(a[1]);
            lk[key][d0 + 2] = f2bf(a[2]); lk[key][d0 + 3] = f2bf(a[3]);
            lk[key][d0 + 4] = f2bf(c[0]); lk[key][d0 + 5] = f2bf(c[1]);
            lk[key][d0 + 6] = f2bf(c[2]); lk[key][d0 + 7] = f2bf(c[3]);
        }
        __syncthreads();
        {
            const int l = t & 63, dt = t >> 6;
            const int j = l & 15, g = l >> 4;
            us8 o;
            #pragma unroll
            for (int e = 0; e < 8; ++e) {
                const int key = 16 * (e >> 2) + 4 * g + (e & 3);
                o[e] = lk[key][dt * 16 + j];
            }
            *(us8*)(Vtt + ((size_t)(b * NKT + kt)) * TSZ + t * 8) = o;
        }
    } else {
        // M: fp32 [q][k] -> per-wave-linear bf16 Mt[qt][kt][t]
        bid -= 2048;
        const int qt = bid >> 7;
        const int kt = bid & 127;
        const int l = t & 63, w = t >> 6;
        const int row = w * 16 + (l & 15), g = l >> 4;
        const float* src = M + ((size_t)(qt * QBLK + row)) * S_LEN + kt * KBLK;
        f32x4 a = *(const f32x4*)(src + 4 * g);
        f32x4 c = *(const f32x4*)(src + 16 + 4 * g);
        us8 o;
        o[0] = f2bf(a[0]); o[1] = f2bf(a[1]); o[2] = f2bf(a[2]); o[3] = f2bf(a[3]);
        o[4] = f2bf(c[0]); o[5] = f2bf(c[1]); o[6] = f2bf(c[2]); o[7] = f2bf(c[3]);
        *(us8*)(Mt + ((size_t)(qt * NKT + kt)) * TSZ + t * 8) = o;
    }
}

// ---- attention: fragment-major LDS dbuf, drain-free barriers, unroll-2, split-K ----
template <int SPLITS>
__global__ __launch_bounds__(256)
void attn_frag(const float* __restrict__ Q,
               const unsigned short* __restrict__ Ktt,
               const unsigned short* __restrict__ Vtt,
               const unsigned short* __restrict__ Mt,
               float* __restrict__ Pacc, float* __restrict__ Plsum,
               float* __restrict__ O) {
    // S: K buf0 [0,2048), K buf1 [2048,4096), V buf0 [4096,6144), V buf1 [6144,8192)
    __shared__ __align__(16) unsigned short S[8192];   // 16 KB

    const int t    = threadIdx.x;
    const int wave = t >> 6;
    const int l    = t & 63;
    const int g    = l >> 4;
    const int j    = l & 15;

    const int bid = blockIdx.x;
    const int b   = bid & 7;             // batch <-> XCD (K/V L2-resident)
    const int qt  = (bid >> 3) & 63;
    const int sp  = (SPLITS > 1) ? (bid >> 9) : 0;
    const int nsteps = NKT / SPLITS;
    const int qrow = qt * QBLK + wave * 16 + j;
    const size_t row = (size_t)b * S_LEN + qrow;

    const float* Qb = Q + (size_t)b * S_LEN * DMODEL;
    const bf16x8 qf0 = cvt8s(Qb + (size_t)qrow * DMODEL + g * 8, QSCALE);
    const bf16x8 qf1 = cvt8s(Qb + (size_t)qrow * DMODEL + g * 8 + 32, QSCALE);

    bf16x8 vones;
    #pragma unroll
    for (int e = 0; e < 8; ++e) vones[e] = (short)0x3F80;

    f32x4 acc[4];
    #pragma unroll
    for (int dt = 0; dt < 4; ++dt) acc[dt] = f32x4{0.f, 0.f, 0.f, 0.f};
    f32x4 accl = {0.f, 0.f, 0.f, 0.f};

    const int kt0 = sp * nsteps;
    const unsigned short* pk = Ktt + (size_t)(b * NKT + kt0) * TSZ + t * 8;
    const unsigned short* pv = Vtt + (size_t)(b * NKT + kt0) * TSZ + t * 8;
    const unsigned short* pm = Mt  + (size_t)(qt * NKT + kt0) * TSZ + t * 8;

    // ---- prologue: tile kt0 -> buf0; tile kt0+1 -> regs; masks kt0/kt0+1 -> mA/mB ----
    us8 kreg = *(const us8*)pk;
    us8 vreg = *(const us8*)pv;
    us8 mA   = *(const us8*)pm;
    *(us8*)&S[t * 8]        = kreg;
    *(us8*)&S[4096 + t * 8] = vreg;
    kreg = *(const us8*)(pk + TSZ);
    vreg = *(const us8*)(pv + TSZ);
    us8 mB = *(const us8*)(pm + TSZ);
    pk += 2 * TSZ; pv += 2 * TSZ; pm += 2 * TSZ;   // now point at tile s+2
    LDS_BARRIER();

    // NOTE: prefetch pointers overrun the split range by 1-2 tiles at the end;
    // those reads land in adjacent ws arrays (in-bounds) and are never consumed.
    for (int p = 0; p < nsteps / 2; ++p) {
        #pragma unroll
        for (int u = 0; u < 2; ++u) {
            // 1) stage tile s+1 (in regs) into buf u^1 — linear t*16, conflict-free
            //    (compiler inserts counted vmcnt waits here for the in-flight loads)
            *(us8*)&S[(u ^ 1) * 2048 + t * 8]        = kreg;
            *(us8*)&S[4096 + (u ^ 1) * 2048 + t * 8] = vreg;

            // 2) issue loads for tile s+2 — they may span the next barrier
            kreg = *(const us8*)pk; pk += TSZ;
            vreg = *(const us8*)pv; pv += TSZ;

            // 3) compute step s from buf u (static offsets via unroll)
            bf16x8 kf0 = *(const bf16x8*)&S[u * 2048 + 0 * 512 + l * 8];
            bf16x8 kf1 = *(const bf16x8*)&S[u * 2048 + 1 * 512 + l * 8];
            bf16x8 kf2 = *(const bf16x8*)&S[u * 2048 + 2 * 512 + l * 8];
            bf16x8 kf3 = *(const bf16x8*)&S[u * 2048 + 3 * 512 + l * 8];

            f32x4 st0 = {0.f, 0.f, 0.f, 0.f};
            f32x4 st1 = {0.f, 0.f, 0.f, 0.f};
            st0 = __builtin_amdgcn_mfma_f32_16x16x32_bf16(kf0, qf0, st0, 0, 0, 0);
            st0 = __builtin_amdgcn_mfma_f32_16x16x32_bf16(kf1, qf1, st0, 0, 0, 0);
            st1 = __builtin_amdgcn_mfma_f32_16x16x32_bf16(kf2, qf0, st1, 0, 0, 0);
            st1 = __builtin_amdgcn_mfma_f32_16x16x32_bf16(kf3, qf1, st1, 0, 0, 0);
            // st0[r]: key kb+4g+r, st1[r]: key kb+16+4g+r, column q = qrow

            const us8 mcur = u ? mB : mA;
            float e0[4], e1[4];
            #pragma unroll
            for (int r = 0; r < 4; ++r) {
                e0[r] = __builtin_amdgcn_exp2f(st0[r]) * bf2f(mcur[r]);
                e1[r] = __builtin_amdgcn_exp2f(st1[r]) * bf2f(mcur[4 + r]);
            }
            u32x4 pw;
            pw[0] = packbf2(e0[0], e0[1]);
            pw[1] = packbf2(e0[2], e0[3]);
            pw[2] = packbf2(e1[0], e1[1]);
            pw[3] = packbf2(e1[2], e1[3]);
            const bf16x8 pf = __builtin_bit_cast(bf16x8, pw);  // slot e: key kb+16*(e>>2)+4g+(e&3)

            // 4) reload mask for step s+2 into the same (static) slot
            if (u == 0) { mA = *(const us8*)pm; } else { mB = *(const us8*)pm; }
            pm += TSZ;

            accl = __builtin_amdgcn_mfma_f32_16x16x32_bf16(vones, pf, accl, 0, 0, 0);
            #pragma unroll
            for (int dt = 0; dt < 4; ++dt) {
                bf16x8 vf = *(const bf16x8*)&S[4096 + u * 2048 + dt * 512 + l * 8];
                acc[dt] = __builtin_amdgcn_mfma_f32_16x16x32_bf16(vf, pf, acc[dt], 0, 0, 0);
            }

            // 5) drain-free barrier: LDS ops ordered, global prefetches stay in flight
            LDS_BARRIER();
        }
    }

    const float lsum = accl[0];   // ones^T*P: full split-sum in every reg

    if (SPLITS > 1) {
        if (g == 0) Plsum[(size_t)sp * NROWS + row] = lsum;
        float* pr = Pacc + ((size_t)sp * NROWS + row) * DMODEL;
        #pragma unroll
        for (int dt = 0; dt < 4; ++dt)
            *(f32x4*)(pr + dt * 16 + g * 4) = acc[dt];
    } else {
        const float inv = 1.0f / lsum;
        float* orow = O + row * DMODEL;
        #pragma unroll
        for (int dt = 0; dt < 4; ++dt) {
            f32x4 o;
            #pragma unroll
            for (int r = 0; r < 4; ++r) o[r] = acc[dt][r] * inv;
            *(f32x4*)(orow + dt * 16 + g * 4) = o;
        }
    }
}

// ---- reduce: O = sum_s acc_s / sum_s lsum_s ----
__global__ __launch_bounds__(256)
void reduce_split(const float* __restrict__ Pacc, const float* __restrict__ Plsum,
                  float* __restrict__ O) {
    const int t = threadIdx.x;
    const size_t rid = (size_t)blockIdx.x * 16 + (t >> 4);
    const int seg = (t & 15) * 4;

    float ls = 0.f;
    f32x4 a = {0.f, 0.f, 0.f, 0.f};
    #pragma unroll
    for (int s = 0; s < NSPLIT; ++s) {
        ls += Plsum[(size_t)s * NROWS + rid];
        f32x4 v = *(const f32x4*)(Pacc + ((size_t)s * NROWS + rid) * DMODEL + seg);
        a[0] += v[0]; a[1] += v[1]; a[2] += v[2]; a[3] += v[3];
    }
    const float inv = 1.0f / ls;
    f32x4 o = {a[0] * inv, a[1] * inv, a[2] * inv, a[3] * inv};
    *(f32x4*)(O + rid * DMODEL + seg) = o;
}

// ---- no-workspace fallback: direct fp32 loads (validated math) ----
__global__ __launch_bounds__(256)
void attn_fb(const float* __restrict__ Q, const float* __restrict__ Kf,
             const float* __restrict__ Vf, const float* __restrict__ M,
             float* __restrict__ O) {
    const int t    = threadIdx.x;
    const int wave = t >> 6;
    const int lane = t & 63;
    const int g    = lane >> 4;
    const int j    = lane & 15;
    const int bid  = blockIdx.x;
    const int b    = bid & 7;
    const int qt   = bid >> 3;
    const int qrow = qt * QBLK + wave * 16 + j;

    const float* Qb = Q + (size_t)b * S_LEN * DMODEL;
    const bf16x8 qf0 = cvt8s(Qb + (size_t)qrow * DMODEL + g * 8, QSCALE);
    const bf16x8 qf1 = cvt8s(Qb + (size_t)qrow * DMODEL + g * 8 + 32, QSCALE);

    f32x4 acc[4];
    #pragma unroll
    for (int dt = 0; dt < 4; ++dt) acc[dt] = f32x4{0.f, 0.f, 0.f, 0.f};
    float lsum = 0.f;

    const float* Kfb = Kf + (size_t)b * S_LEN * DMODEL;
    const float* Vfb = Vf + (size_t)b * S_LEN * DMODEL;
    const float* mrow = M + (size_t)qrow * S_LEN;

    int kg[8];
    #pragma unroll
    for (int e = 0; e < 8; ++e) kg[e] = 16 * (e >> 2) + 4 * g + (e & 3);

    for (int kt = 0; kt < NKT; ++kt) {
        const int kb = kt * KBLK;
        bf16x8 kf00 = cvt8s(Kfb + (size_t)(kb + j) * DMODEL + g * 8, 1.0f);
        bf16x8 kf01 = cvt8s(Kfb + (size_t)(kb + j) * DMODEL + g * 8 + 32, 1.0f);
        bf16x8 kf10 = cvt8s(Kfb + (size_t)(kb + 16 + j) * DMODEL + g * 8, 1.0f);
        bf16x8 kf11 = cvt8s(Kfb + (size_t)(kb + 16 + j) * DMODEL + g * 8 + 32, 1.0f);

        f32x4 st0 = {0.f, 0.f, 0.f, 0.f};
        f32x4 st1 = {0.f, 0.f, 0.f, 0.f};
        st0 = __builtin_amdgcn_mfma_f32_16x16x32_bf16(kf00, qf0, st0, 0, 0, 0);
        st0 = __builtin_amdgcn_mfma_f32_16x16x32_bf16(kf01, qf1, st0, 0, 0, 0);
        st1 = __builtin_amdgcn_mfma_f32_16x16x32_bf16(kf10, qf0, st1, 0, 0, 0);
        st1 = __builtin_amdgcn_mfma_f32_16x16x32_bf16(kf11, qf1, st1, 0, 0, 0);

        f32x4 m0 = *(const f32x4*)(mrow + kb + g * 4);
        f32x4 m1 = *(const f32x4*)(mrow + kb + 16 + g * 4);

        bf16x8 pf;
        #pragma unroll
        for (int r = 0; r < 4; ++r) {
            float w0 = __builtin_amdgcn_exp2f(st0[r]) * m0[r];
            float w1 = __builtin_amdgcn_exp2f(st1[r]) * m1[r];
            lsum += w0 + w1;
            pf[r]     = (short)f2bf(w0);
            pf[4 + r] = (short)f2bf(w1);
        }

        #pragma unroll
        for (int dt = 0; dt < 4; ++dt) {
            bf16x8 vf;
            #pragma unroll
            for (int e = 0; e < 8; ++e)
                vf[e] = (short)f2bf(Vfb[(size_t)(kb + kg[e]) * DMODEL + dt * 16 + j]);
            acc[dt] = __builtin_amdgcn_mfma_f32_16x16x32_bf16(vf, pf, acc[dt], 0, 0, 0);
        }
    }

    lsum += __shfl_xor(lsum, 16, 64);
    lsum += __shfl_xor(lsum, 32, 64);
    const float inv = 1.0f / lsum;

    float* orow = O + ((size_t)b * S_LEN + qrow) * DMODEL;
    #pragma unroll
    for (int dt = 0; dt < 4; ++dt) {
        f32x4 o;
        #pragma unroll
        for (int r = 0; r < 4; ++r) o[r] = acc[dt][r] * inv;
        *(f32x4*)(orow + dt * 16 + g * 4) = o;
    }
}

extern "C" void kernel_launch(void* const* d_in, const int* in_sizes, int n_in,
                              void* d_out, int out_size, void* d_ws, size_t ws_size,
                              hipStream_t stream) {
    const float* Q = (const float*)d_in[0];
    const float* K = (const float*)d_in[1];
    const float* V = (const float*)d_in[2];
    const float* M = (const float*)d_in[3];
    float* O = (float*)d_out;

    const size_t bytes_kv = 2 * NELEM * 2;                           //  8 MB
    const size_t bytes_m  = (size_t)S_LEN * S_LEN * 2;               // 32 MB
    const size_t bytes_ls = (size_t)NSPLIT * NROWS * 4;              //  0.5 MB
    const size_t bytes_pa = (size_t)NSPLIT * NROWS * DMODEL * 4;     // 33.5 MB
    const size_t need_full = bytes_kv + bytes_m + bytes_ls + bytes_pa;  // 74 MB

    if (ws_size >= need_full) {
        unsigned short* Ktt = (unsigned short*)d_ws;
        unsigned short* Vtt = Ktt + NELEM;
        unsigned short* Mt  = Vtt + NELEM;
        float* Plsum = (float*)((char*)d_ws + bytes_kv + bytes_m);
        float* Pacc  = Plsum + NSPLIT * NROWS;
        convert_all<<<10240, 256, 0, stream>>>(K, V, M, Ktt, Vtt, Mt);
        attn_frag<NSPLIT><<<512 * NSPLIT, 256, 0, stream>>>(
            Q, Ktt, Vtt, Mt, Pacc, Plsum, O);
        reduce_split<<<(int)(NROWS / 16), 256, 0, stream>>>(Pacc, Plsum, O);
    } else {
        attn_fb<<<512, 256, 0, stream>>>(Q, K, V, M, O);
    }
}

// Round 14
// 90.179 us; speedup vs baseline: 3.3986x; 1.1497x over previous
//
#include <hip/hip_runtime.h>
#include <hip/hip_bf16.h>

#define S_LEN 4096
#define DMODEL 64
#define QBLK 128
#define NQT (S_LEN / QBLK)                  // 32 q-tiles
#define KBLK 32
#define NKT (S_LEN / KBLK)                  // 128 k-tiles
#define NSPLIT 4
#define NROWS ((size_t)8 * S_LEN)           // 32768 (b,q) rows
#define NELEM ((size_t)8 * S_LEN * DMODEL)  // per-tensor elements (Q/K/V)
#define TSZ 2048                            // elements per staging sub-tile (4KB bf16)
#define QSCALE 0.180336880f                 // 0.125 * log2(e)

typedef __attribute__((ext_vector_type(8))) short bf16x8;
typedef __attribute__((ext_vector_type(4))) float f32x4;
typedef __attribute__((ext_vector_type(8))) unsigned short us8;
typedef __attribute__((ext_vector_type(4))) unsigned int u32x4;

// barrier without the vmcnt(0) drain (LDS visibility needs only lgkmcnt)
#define LDS_BARRIER()                                            \
    do {                                                         \
        asm volatile("s_waitcnt lgkmcnt(0)" ::: "memory");       \
        __builtin_amdgcn_s_barrier();                            \
    } while (0)

__device__ __forceinline__ float bf2f(unsigned short u) {
    unsigned int x = ((unsigned int)u) << 16;
    return __builtin_bit_cast(float, x);
}
__device__ __forceinline__ unsigned short f2bf(float f) {
    unsigned int u = __builtin_bit_cast(unsigned int, f);
    u += 0x7FFFu + ((u >> 16) & 1u);   // RNE
    return (unsigned short)(u >> 16);
}
__device__ __forceinline__ unsigned int packbf2(float lo, float hi) {
    __hip_bfloat162 h = __float22bfloat162_rn(float2{lo, hi});
    unsigned int w;
    __builtin_memcpy(&w, &h, sizeof(w));
    return w;
}
__device__ __forceinline__ bf16x8 cvt8s(const float* __restrict__ p, float c) {
    f32x4 a = *(const f32x4*)p;
    f32x4 b = *(const f32x4*)(p + 4);
    bf16x8 r;
    r[0] = (short)f2bf(a[0] * c); r[1] = (short)f2bf(a[1] * c);
    r[2] = (short)f2bf(a[2] * c); r[3] = (short)f2bf(a[3] * c);
    r[4] = (short)f2bf(b[0] * c); r[5] = (short)f2bf(b[1] * c);
    r[6] = (short)f2bf(b[2] * c); r[7] = (short)f2bf(b[3] * c);
    return r;
}

// ---- fused converts. blocks [0,1024): K, [1024,2048): V, [2048,10240): M ----
__global__ __launch_bounds__(256)
void convert_all(const float* __restrict__ K, const float* __restrict__ V,
                 const float* __restrict__ M,
                 unsigned short* __restrict__ Ktt, unsigned short* __restrict__ Vtt,
                 unsigned short* __restrict__ Mt) {
    const int t = threadIdx.x;
    int bid = blockIdx.x;

    if (bid < 1024) {
        // K -> fragment-major Ktt[b][kt][frag][lane]
        const int b  = bid >> 7;
        const int kt = bid & 127;
        const int l = t & 63, frag = t >> 6;
        const int j = l & 15, g = l >> 4;
        const int row = kt * KBLK + ((frag >> 1) & 1) * 16 + j;
        const int col = (frag & 1) * 32 + g * 8;
        const float* src = K + ((size_t)b * S_LEN + row) * DMODEL + col;
        f32x4 a = *(const f32x4*)src;
        f32x4 c = *(const f32x4*)(src + 4);
        us8 o;
        o[0] = f2bf(a[0]); o[1] = f2bf(a[1]); o[2] = f2bf(a[2]); o[3] = f2bf(a[3]);
        o[4] = f2bf(c[0]); o[5] = f2bf(c[1]); o[6] = f2bf(c[2]); o[7] = f2bf(c[3]);
        *(us8*)(Ktt + ((size_t)(b * NKT + kt)) * TSZ + t * 8) = o;
    } else if (bid < 2048) {
        // V -> fragment-major Vtt[b][kt][dt][lane] (transpose via LDS)
        bid -= 1024;
        __shared__ unsigned short lk[KBLK][68];
        const int b  = bid >> 7;
        const int kt = bid & 127;
        {
            const int key = t >> 3, d0 = (t & 7) * 8;
            const float* src = V + ((size_t)b * S_LEN + kt * KBLK + key) * DMODEL + d0;
            f32x4 a = *(const f32x4*)src;
            f32x4 c = *(const f32x4*)(src + 4);
            lk[key][d0 + 0] = f2bf(a[0]); lk[key][d0 + 1] = f2bf(a[1]);
            lk[key][d0 + 2] = f2bf(a[2]); lk[key][d0 + 3] = f2bf(a[3]);
            lk[key][d0 + 4] = f2bf(c[0]); lk[key][d0 + 5] = f2bf(c[1]);
            lk[key][d0 + 6] = f2bf(c[2]); lk[key][d0 + 7] = f2bf(c[3]);
        }
        __syncthreads();
        {
            const int l = t & 63, dt = t >> 6;
            const int j = l & 15, g = l >> 4;
            us8 o;
            #pragma unroll
            for (int e = 0; e < 8; ++e) {
                const int key = 16 * (e >> 2) + 4 * g + (e & 3);
                o[e] = lk[key][dt * 16 + j];
            }
            *(us8*)(Vtt + ((size_t)(b * NKT + kt)) * TSZ + t * 8) = o;
        }
    } else {
        // M -> per-wave-linear bf16 Mt[qt][kt][h][t]; h = q-subgroup (16 rows)
        bid -= 2048;                         // [0, 8192)
        const int qt  = bid >> 8;            // 0..31
        const int rem = bid & 255;
        const int kt  = rem >> 1;            // 0..127
        const int h   = rem & 1;
        const int l = t & 63, w = t >> 6;
        const int j = l & 15, g = l >> 4;
        const int row = qt * QBLK + w * 32 + h * 16 + j;
        const float* src = M + ((size_t)row) * S_LEN + kt * KBLK;
        f32x4 a = *(const f32x4*)(src + 4 * g);
        f32x4 c = *(const f32x4*)(src + 16 + 4 * g);
        us8 o;
        o[0] = f2bf(a[0]); o[1] = f2bf(a[1]); o[2] = f2bf(a[2]); o[3] = f2bf(a[3]);
        o[4] = f2bf(c[0]); o[5] = f2bf(c[1]); o[6] = f2bf(c[2]); o[7] = f2bf(c[3]);
        *(us8*)(Mt + (((size_t)(qt * NKT + kt)) * 2 + h) * TSZ + t * 8) = o;
    }
}

// ---- attention: QBLK=128 (2 q-groups/wave), fragment-major LDS dbuf, split-K ----
template <int SPLITS>
__global__ __launch_bounds__(256, 4)
void attn_frag(const float* __restrict__ Q,
               const unsigned short* __restrict__ Ktt,
               const unsigned short* __restrict__ Vtt,
               const unsigned short* __restrict__ Mt,
               float* __restrict__ Pacc, float* __restrict__ Plsum,
               float* __restrict__ O) {
    // S: K buf0 [0,2048), K buf1 [2048,4096), V buf0 [4096,6144), V buf1 [6144,8192)
    __shared__ __align__(16) unsigned short S[8192];   // 16 KB

    const int t    = threadIdx.x;
    const int wave = t >> 6;
    const int l    = t & 63;
    const int g    = l >> 4;
    const int j    = l & 15;

    const int bid = blockIdx.x;
    const int b   = bid & 7;             // batch <-> XCD (K/V L2-resident)
    const int qt  = (bid >> 3) & 31;
    const int sp  = (SPLITS > 1) ? (bid >> 8) : 0;
    const int nsteps = NKT / SPLITS;
    const int qrowA = qt * QBLK + wave * 32 + j;
    const int qrowB = qrowA + 16;
    const size_t rowA = (size_t)b * S_LEN + qrowA;
    const size_t rowB = rowA + 16;

    const float* Qb = Q + (size_t)b * S_LEN * DMODEL;
    const bf16x8 qf0a = cvt8s(Qb + (size_t)qrowA * DMODEL + g * 8, QSCALE);
    const bf16x8 qf1a = cvt8s(Qb + (size_t)qrowA * DMODEL + g * 8 + 32, QSCALE);
    const bf16x8 qf0b = cvt8s(Qb + (size_t)qrowB * DMODEL + g * 8, QSCALE);
    const bf16x8 qf1b = cvt8s(Qb + (size_t)qrowB * DMODEL + g * 8 + 32, QSCALE);

    bf16x8 vones;
    #pragma unroll
    for (int e = 0; e < 8; ++e) vones[e] = (short)0x3F80;

    f32x4 accA[4], accB[4];
    #pragma unroll
    for (int dt = 0; dt < 4; ++dt) {
        accA[dt] = f32x4{0.f, 0.f, 0.f, 0.f};
        accB[dt] = f32x4{0.f, 0.f, 0.f, 0.f};
    }
    f32x4 acclA = {0.f, 0.f, 0.f, 0.f};
    f32x4 acclB = {0.f, 0.f, 0.f, 0.f};

    const int kt0 = sp * nsteps;
    const unsigned short* pk = Ktt + (size_t)(b * NKT + kt0) * TSZ + t * 8;
    const unsigned short* pv = Vtt + (size_t)(b * NKT + kt0) * TSZ + t * 8;
    const unsigned short* pm = Mt + ((size_t)(qt * NKT + kt0) * 2) * TSZ + t * 8;

    // ---- prologue: tile kt0 -> buf0; tile kt0+1 -> regs; masks for both ----
    us8 kreg = *(const us8*)pk;
    us8 vreg = *(const us8*)pv;
    us8 mA0 = *(const us8*)pm;
    us8 mA1 = *(const us8*)(pm + TSZ);
    *(us8*)&S[t * 8]        = kreg;
    *(us8*)&S[4096 + t * 8] = vreg;
    kreg = *(const us8*)(pk + TSZ);
    vreg = *(const us8*)(pv + TSZ);
    us8 mB0 = *(const us8*)(pm + 2 * TSZ);
    us8 mB1 = *(const us8*)(pm + 3 * TSZ);
    pk += 2 * TSZ; pv += 2 * TSZ; pm += 4 * TSZ;   // -> tile s+2
    LDS_BARRIER();

    // Prefetch pointers overrun the split range by <=2 tiles at the end; those
    // reads land in the adjacent ws arrays (in-bounds) and are never consumed.
    for (int p = 0; p < nsteps / 2; ++p) {
        #pragma unroll
        for (int u = 0; u < 2; ++u) {
            // 1) stage tile s+1 into buf u^1 — linear t*16, conflict-free
            *(us8*)&S[(u ^ 1) * 2048 + t * 8]        = kreg;
            *(us8*)&S[4096 + (u ^ 1) * 2048 + t * 8] = vreg;

            // 2) issue loads for tile s+2
            kreg = *(const us8*)pk; pk += TSZ;
            vreg = *(const us8*)pv; pv += TSZ;

            // 3) compute step s from buf u (static offsets via unroll)
            bf16x8 kf0 = *(const bf16x8*)&S[u * 2048 + 0 * 512 + l * 8];
            bf16x8 kf1 = *(const bf16x8*)&S[u * 2048 + 1 * 512 + l * 8];
            bf16x8 kf2 = *(const bf16x8*)&S[u * 2048 + 2 * 512 + l * 8];
            bf16x8 kf3 = *(const bf16x8*)&S[u * 2048 + 3 * 512 + l * 8];

            f32x4 sA0 = {0.f, 0.f, 0.f, 0.f}, sA1 = {0.f, 0.f, 0.f, 0.f};
            f32x4 sB0 = {0.f, 0.f, 0.f, 0.f}, sB1 = {0.f, 0.f, 0.f, 0.f};
            sA0 = __builtin_amdgcn_mfma_f32_16x16x32_bf16(kf0, qf0a, sA0, 0, 0, 0);
            sB0 = __builtin_amdgcn_mfma_f32_16x16x32_bf16(kf0, qf0b, sB0, 0, 0, 0);
            sA0 = __builtin_amdgcn_mfma_f32_16x16x32_bf16(kf1, qf1a, sA0, 0, 0, 0);
            sB0 = __builtin_amdgcn_mfma_f32_16x16x32_bf16(kf1, qf1b, sB0, 0, 0, 0);
            sA1 = __builtin_amdgcn_mfma_f32_16x16x32_bf16(kf2, qf0a, sA1, 0, 0, 0);
            sB1 = __builtin_amdgcn_mfma_f32_16x16x32_bf16(kf2, qf0b, sB1, 0, 0, 0);
            sA1 = __builtin_amdgcn_mfma_f32_16x16x32_bf16(kf3, qf1a, sA1, 0, 0, 0);
            sB1 = __builtin_amdgcn_mfma_f32_16x16x32_bf16(kf3, qf1b, sB1, 0, 0, 0);
            // s{A,B}0[r]: key kb+4g+r; s{A,B}1[r]: key kb+16+4g+r; col = qrow{A,B}

            const us8 m0 = u ? mB0 : mA0;
            const us8 m1 = u ? mB1 : mA1;

            float eA0[4], eA1[4], eB0[4], eB1[4];
            #pragma unroll
            for (int r = 0; r < 4; ++r) {
                eA0[r] = __builtin_amdgcn_exp2f(sA0[r]) * bf2f(m0[r]);
                eA1[r] = __builtin_amdgcn_exp2f(sA1[r]) * bf2f(m0[4 + r]);
                eB0[r] = __builtin_amdgcn_exp2f(sB0[r]) * bf2f(m1[r]);
                eB1[r] = __builtin_amdgcn_exp2f(sB1[r]) * bf2f(m1[4 + r]);
            }
            u32x4 pwA, pwB;
            pwA[0] = packbf2(eA0[0], eA0[1]); pwA[1] = packbf2(eA0[2], eA0[3]);
            pwA[2] = packbf2(eA1[0], eA1[1]); pwA[3] = packbf2(eA1[2], eA1[3]);
            pwB[0] = packbf2(eB0[0], eB0[1]); pwB[1] = packbf2(eB0[2], eB0[3]);
            pwB[2] = packbf2(eB1[0], eB1[1]); pwB[3] = packbf2(eB1[2], eB1[3]);
            const bf16x8 pfA = __builtin_bit_cast(bf16x8, pwA);
            const bf16x8 pfB = __builtin_bit_cast(bf16x8, pwB);

            // 4) reload masks for step s+2 into the same (static) slots
            if (u == 0) { mA0 = *(const us8*)pm; mA1 = *(const us8*)(pm + TSZ); }
            else        { mB0 = *(const us8*)pm; mB1 = *(const us8*)(pm + TSZ); }
            pm += 2 * TSZ;

            acclA = __builtin_amdgcn_mfma_f32_16x16x32_bf16(vones, pfA, acclA, 0, 0, 0);
            acclB = __builtin_amdgcn_mfma_f32_16x16x32_bf16(vones, pfB, acclB, 0, 0, 0);
            #pragma unroll
            for (int dt = 0; dt < 4; ++dt) {
                bf16x8 vf = *(const bf16x8*)&S[4096 + u * 2048 + dt * 512 + l * 8];
                accA[dt] = __builtin_amdgcn_mfma_f32_16x16x32_bf16(vf, pfA, accA[dt], 0, 0, 0);
                accB[dt] = __builtin_amdgcn_mfma_f32_16x16x32_bf16(vf, pfB, accB[dt], 0, 0, 0);
            }

            // 5) drain-free barrier
            LDS_BARRIER();
        }
    }

    const float lsumA = acclA[0];   // full split-sum for col qrowA (all rows equal)
    const float lsumB = acclB[0];

    if (SPLITS > 1) {
        if (g == 0) {
            Plsum[(size_t)sp * NROWS + rowA] = lsumA;
            Plsum[(size_t)sp * NROWS + rowB] = lsumB;
        }
        float* prA = Pacc + ((size_t)sp * NROWS + rowA) * DMODEL;
        float* prB = Pacc + ((size_t)sp * NROWS + rowB) * DMODEL;
        #pragma unroll
        for (int dt = 0; dt < 4; ++dt) {
            *(f32x4*)(prA + dt * 16 + g * 4) = accA[dt];
            *(f32x4*)(prB + dt * 16 + g * 4) = accB[dt];
        }
    } else {
        const float invA = 1.0f / lsumA;
        const float invB = 1.0f / lsumB;
        float* orA = O + rowA * DMODEL;
        float* orB = O + rowB * DMODEL;
        #pragma unroll
        for (int dt = 0; dt < 4; ++dt) {
            f32x4 oa, ob;
            #pragma unroll
            for (int r = 0; r < 4; ++r) { oa[r] = accA[dt][r] * invA; ob[r] = accB[dt][r] * invB; }
            *(f32x4*)(orA + dt * 16 + g * 4) = oa;
            *(f32x4*)(orB + dt * 16 + g * 4) = ob;
        }
    }
}

// ---- reduce: O = sum_s acc_s / sum_s lsum_s ----
__global__ __launch_bounds__(256)
void reduce_split(const float* __restrict__ Pacc, const float* __restrict__ Plsum,
                  float* __restrict__ O) {
    const int t = threadIdx.x;
    const size_t rid = (size_t)blockIdx.x * 16 + (t >> 4);
    const int seg = (t & 15) * 4;

    float ls = 0.f;
    f32x4 a = {0.f, 0.f, 0.f, 0.f};
    #pragma unroll
    for (int s = 0; s < NSPLIT; ++s) {
        ls += Plsum[(size_t)s * NROWS + rid];
        f32x4 v = *(const f32x4*)(Pacc + ((size_t)s * NROWS + rid) * DMODEL + seg);
        a[0] += v[0]; a[1] += v[1]; a[2] += v[2]; a[3] += v[3];
    }
    const float inv = 1.0f / ls;
    f32x4 o = {a[0] * inv, a[1] * inv, a[2] * inv, a[3] * inv};
    *(f32x4*)(O + rid * DMODEL + seg) = o;
}

// ---- no-workspace fallback: direct fp32 loads (validated math, QBLK=64 grid) ----
__global__ __launch_bounds__(256)
void attn_fb(const float* __restrict__ Q, const float* __restrict__ Kf,
             const float* __restrict__ Vf, const float* __restrict__ M,
             float* __restrict__ O) {
    const int t    = threadIdx.x;
    const int wave = t >> 6;
    const int lane = t & 63;
    const int g    = lane >> 4;
    const int j    = lane & 15;
    const int bid  = blockIdx.x;
    const int b    = bid & 7;
    const int qt   = bid >> 3;
    const int qrow = qt * 64 + wave * 16 + j;

    const float* Qb = Q + (size_t)b * S_LEN * DMODEL;
    const bf16x8 qf0 = cvt8s(Qb + (size_t)qrow * DMODEL + g * 8, QSCALE);
    const bf16x8 qf1 = cvt8s(Qb + (size_t)qrow * DMODEL + g * 8 + 32, QSCALE);

    f32x4 acc[4];
    #pragma unroll
    for (int dt = 0; dt < 4; ++dt) acc[dt] = f32x4{0.f, 0.f, 0.f, 0.f};
    float lsum = 0.f;

    const float* Kfb = Kf + (size_t)b * S_LEN * DMODEL;
    const float* Vfb = Vf + (size_t)b * S_LEN * DMODEL;
    const float* mrow = M + (size_t)qrow * S_LEN;

    int kg[8];
    #pragma unroll
    for (int e = 0; e < 8; ++e) kg[e] = 16 * (e >> 2) + 4 * g + (e & 3);

    for (int kt = 0; kt < NKT; ++kt) {
        const int kb = kt * KBLK;
        bf16x8 kf00 = cvt8s(Kfb + (size_t)(kb + j) * DMODEL + g * 8, 1.0f);
        bf16x8 kf01 = cvt8s(Kfb + (size_t)(kb + j) * DMODEL + g * 8 + 32, 1.0f);
        bf16x8 kf10 = cvt8s(Kfb + (size_t)(kb + 16 + j) * DMODEL + g * 8, 1.0f);
        bf16x8 kf11 = cvt8s(Kfb + (size_t)(kb + 16 + j) * DMODEL + g * 8 + 32, 1.0f);

        f32x4 st0 = {0.f, 0.f, 0.f, 0.f};
        f32x4 st1 = {0.f, 0.f, 0.f, 0.f};
        st0 = __builtin_amdgcn_mfma_f32_16x16x32_bf16(kf00, qf0, st0, 0, 0, 0);
        st0 = __builtin_amdgcn_mfma_f32_16x16x32_bf16(kf01, qf1, st0, 0, 0, 0);
        st1 = __builtin_amdgcn_mfma_f32_16x16x32_bf16(kf10, qf0, st1, 0, 0, 0);
        st1 = __builtin_amdgcn_mfma_f32_16x16x32_bf16(kf11, qf1, st1, 0, 0, 0);

        f32x4 m0 = *(const f32x4*)(mrow + kb + g * 4);
        f32x4 m1 = *(const f32x4*)(mrow + kb + 16 + g * 4);

        bf16x8 pf;
        #pragma unroll
        for (int r = 0; r < 4; ++r) {
            float w0 = __builtin_amdgcn_exp2f(st0[r]) * m0[r];
            float w1 = __builtin_amdgcn_exp2f(st1[r]) * m1[r];
            lsum += w0 + w1;
            pf[r]     = (short)f2bf(w0);
            pf[4 + r] = (short)f2bf(w1);
        }

        #pragma unroll
        for (int dt = 0; dt < 4; ++dt) {
            bf16x8 vf;
            #pragma unroll
            for (int e = 0; e < 8; ++e)
                vf[e] = (short)f2bf(Vfb[(size_t)(kb + kg[e]) * DMODEL + dt * 16 + j]);
            acc[dt] = __builtin_amdgcn_mfma_f32_16x16x32_bf16(vf, pf, acc[dt], 0, 0, 0);
        }
    }

    lsum += __shfl_xor(lsum, 16, 64);
    lsum += __shfl_xor(lsum, 32, 64);
    const float inv = 1.0f / lsum;

    float* orow = O + ((size_t)b * S_LEN + qrow) * DMODEL;
    #pragma unroll
    for (int dt = 0; dt < 4; ++dt) {
        f32x4 o;
        #pragma unroll
        for (int r = 0; r < 4; ++r) o[r] = acc[dt][r] * inv;
        *(f32x4*)(orow + dt * 16 + g * 4) = o;
    }
}

extern "C" void kernel_launch(void* const* d_in, const int* in_sizes, int n_in,
                              void* d_out, int out_size, void* d_ws, size_t ws_size,
                              hipStream_t stream) {
    const float* Q = (const float*)d_in[0];
    const float* K = (const float*)d_in[1];
    const float* V = (const float*)d_in[2];
    const float* M = (const float*)d_in[3];
    float* O = (float*)d_out;

    const size_t bytes_kv = 2 * NELEM * 2;                           //  8 MB
    const size_t bytes_m  = (size_t)S_LEN * S_LEN * 2;               // 32 MB
    const size_t bytes_ls = (size_t)NSPLIT * NROWS * 4;              //  0.5 MB
    const size_t bytes_pa = (size_t)NSPLIT * NROWS * DMODEL * 4;     // 33.5 MB
    const size_t need_full = bytes_kv + bytes_m + bytes_ls + bytes_pa;  // 74 MB

    if (ws_size >= need_full) {
        unsigned short* Ktt = (unsigned short*)d_ws;
        unsigned short* Vtt = Ktt + NELEM;
        unsigned short* Mt  = Vtt + NELEM;
        float* Plsum = (float*)((char*)d_ws + bytes_kv + bytes_m);
        float* Pacc  = Plsum + NSPLIT * NROWS;
        convert_all<<<10240, 256, 0, stream>>>(K, V, M, Ktt, Vtt, Mt);
        attn_frag<NSPLIT><<<8 * NQT * NSPLIT, 256, 0, stream>>>(
            Q, Ktt, Vtt, Mt, Pacc, Plsum, O);
        reduce_split<<<(int)(NROWS / 16), 256, 0, stream>>>(Pacc, Plsum, O);
    } else {
        attn_fb<<<512, 256, 0, stream>>>(Q, K, V, M, O);
    }
}